// Round 6
// baseline (278.120 us; speedup 1.0000x reference)
//
#include <hip/hip_runtime.h>
#include <cstddef>
#include <cstdint>

constexpr int BATCH = 64;
constexpr int CH    = 256;
constexpr int NPT   = 196;
constexpr int ROWS  = BATCH * NPT;   // 12544
constexpr int BSTRIDE = CH * NPT;    // 50176
constexpr int KNB   = 8;             // position 8 (9th) is never valid: k_int <= 8

typedef __bf16 bf16x8 __attribute__((ext_vector_type(8)));
typedef __bf16 bf16x4 __attribute__((ext_vector_type(4)));
typedef _Float16 f16x8 __attribute__((ext_vector_type(8)));
typedef float  f32x4  __attribute__((ext_vector_type(4)));

__device__ __forceinline__ int src_batch(int b) {
    return (b & ~15) | ((b + 1) & 15);
}

__device__ __forceinline__ void gload_lds16(const void* g, void* l) {
    __builtin_amdgcn_global_load_lds(
        (const __attribute__((address_space(1))) void*)g,
        (__attribute__((address_space(3))) void*)l, 16, 0, 0);
}

// ---------------- qs: per-point squared norm (f32-exact) ----------------
__global__ __launch_bounds__(256) void qs_kernel(const float* __restrict__ x,
                                                 float* __restrict__ qs) {
    int b = blockIdx.x;
    int m = threadIdx.x;
    if (m >= NPT) return;
    const float* xb = x + (size_t)b * BSTRIDE;
    float acc = 0.f;
    for (int c = 0; c < CH; ++c) {
        float v = xb[c * NPT + m];
        acc = fmaf(v, v, acc);
    }
    qs[b * NPT + m] = acc;
}

// ------- transpose + f16 hi/lo split + bf16 copy: x[b][c][m] -> XH/XL[b][m][c], XB=bf16(x) -------
__global__ __launch_bounds__(256) void trans_split(const float* __restrict__ x,
        _Float16* __restrict__ XH, _Float16* __restrict__ XL,
        __bf16* __restrict__ XB) {
    __shared__ float tile[64][65];
    int b = blockIdx.z;
    int m0 = blockIdx.x * 64, c0 = blockIdx.y * 64;
    int t = threadIdx.x;
    const float* xb = x + (size_t)b * BSTRIDE;
    #pragma unroll
    for (int s = 0; s < 16; ++s) {
        int idx = s * 256 + t;
        int cc = idx >> 6, mm = idx & 63;
        int m = m0 + mm;
        float v = (m < NPT) ? xb[(size_t)(c0 + cc) * NPT + m] : 0.f;
        tile[cc][mm] = v;
        if (m < NPT)
            XB[(size_t)b * BSTRIDE + (size_t)(c0 + cc) * NPT + m] = (__bf16)v;
    }
    __syncthreads();
    #pragma unroll
    for (int s = 0; s < 16; ++s) {
        int idx = s * 256 + t;
        int mm = idx >> 6, cc = idx & 63;
        float v = tile[cc][mm];
        _Float16 h = (_Float16)v;
        size_t off = ((size_t)b * 256 + (m0 + mm)) * 256 + c0 + cc;
        XH[off] = h;
        XL[off] = (_Float16)(v - (float)h);
    }
}

// ---------------- Gram via f16-split MFMA: D = Ah*Bh + Ah*Bl + Al*Bh ----------------
__global__ __launch_bounds__(256) void gram_mfma(const _Float16* __restrict__ XH,
        const _Float16* __restrict__ XL, float* __restrict__ D) {
    __shared__ __attribute__((aligned(16))) _Float16 Ah[128 * 64];
    __shared__ __attribute__((aligned(16))) _Float16 Al[128 * 64];
    __shared__ __attribute__((aligned(16))) _Float16 Bh[128 * 64];
    __shared__ __attribute__((aligned(16))) _Float16 Bl[128 * 64];
    int job = blockIdx.z;
    int qb = (job < 64) ? job : job - 64;
    int kb = (job < 64) ? qb : src_batch(qb);
    int t = threadIdx.x, w = t >> 6, l = t & 63;
    int r0 = blockIdx.y * 128, c0 = blockIdx.x * 128;
    int lr = l & 15, lg = l >> 4;
    int wr = (w >> 1) * 64, wc = (w & 1) * 64;
    const _Float16* qh = XH + (size_t)qb * 65536;
    const _Float16* ql = XL + (size_t)qb * 65536;
    const _Float16* kh = XH + (size_t)kb * 65536;
    const _Float16* kl = XL + (size_t)kb * 65536;
    f32x4 acc[4][4] = {};
    for (int k0 = 0; k0 < 256; k0 += 64) {
        #pragma unroll
        for (int i = 0; i < 4; ++i) {
            int row = (w * 4 + i) * 8 + (l >> 3);
            int c8 = l & 7;
            size_t goA = (size_t)(r0 + row) * 256 + k0 + c8 * 8;
            size_t goB = (size_t)(c0 + row) * 256 + k0 + c8 * 8;
            gload_lds16(qh + goA, Ah + (w * 4 + i) * 512);
            gload_lds16(ql + goA, Al + (w * 4 + i) * 512);
            gload_lds16(kh + goB, Bh + (w * 4 + i) * 512);
            gload_lds16(kl + goB, Bl + (w * 4 + i) * 512);
        }
        asm volatile("s_waitcnt vmcnt(0)" ::: "memory");
        __syncthreads();
        #pragma unroll
        for (int ks = 0; ks < 2; ++ks) {
            f16x8 ah[4], al[4], bh[4], bl[4];
            #pragma unroll
            for (int mi = 0; mi < 4; ++mi) {
                ah[mi] = *(const f16x8*)(Ah + (wr + mi * 16 + lr) * 64 + ks * 32 + lg * 8);
                al[mi] = *(const f16x8*)(Al + (wr + mi * 16 + lr) * 64 + ks * 32 + lg * 8);
            }
            #pragma unroll
            for (int ni = 0; ni < 4; ++ni) {
                bh[ni] = *(const f16x8*)(Bh + (wc + ni * 16 + lr) * 64 + ks * 32 + lg * 8);
                bl[ni] = *(const f16x8*)(Bl + (wc + ni * 16 + lr) * 64 + ks * 32 + lg * 8);
            }
            #pragma unroll
            for (int mi = 0; mi < 4; ++mi)
                #pragma unroll
                for (int ni = 0; ni < 4; ++ni) {
                    acc[mi][ni] = __builtin_amdgcn_mfma_f32_16x16x32_f16(
                        ah[mi], bh[ni], acc[mi][ni], 0, 0, 0);
                    acc[mi][ni] = __builtin_amdgcn_mfma_f32_16x16x32_f16(
                        ah[mi], bl[ni], acc[mi][ni], 0, 0, 0);
                    acc[mi][ni] = __builtin_amdgcn_mfma_f32_16x16x32_f16(
                        al[mi], bh[ni], acc[mi][ni], 0, 0, 0);
                }
        }
        __syncthreads();
    }
    #pragma unroll
    for (int mi = 0; mi < 4; ++mi) {
        #pragma unroll
        for (int r = 0; r < 4; ++r) {
            int gi = r0 + wr + mi * 16 + lg * 4 + r;
            if (gi >= NPT) continue;
            #pragma unroll
            for (int ni = 0; ni < 4; ++ni) {
                int gj = c0 + wc + ni * 16 + lr;
                if (gj < NPT)
                    D[(size_t)job * (NPT * NPT) + (size_t)gi * NPT + gj] =
                        acc[mi][ni][r];
            }
        }
    }
}

// ---------------- top-8 selection ----------------
__global__ __launch_bounds__(256) void topk_kernel(const float* __restrict__ D,
                                                   const float* __restrict__ qs,
                                                   int* __restrict__ nbr) {
    int wid = threadIdx.x >> 6;
    int lane = threadIdx.x & 63;
    int rowid = blockIdx.x * 4 + wid;
    int job = rowid / NPT;
    int i = rowid - job * NPT;
    int qb = (job < 64) ? job : job - 64;
    int kb = (job < 64) ? qb : src_batch(qb);
    const float* drow = D + (size_t)job * (NPT * NPT) + (size_t)i * NPT;
    float qsi = qs[qb * NPT + i];
    const float* ksr = qs + kb * NPT;
    float dist[4];
    #pragma unroll
    for (int s = 0; s < 4; ++s) {
        int m = lane + 64 * s;
        dist[s] = (m < NPT) ? (qsi - 2.f * drow[m] + ksr[m])
                            : __uint_as_float(0x7f800000u);
    }
    for (int it = 0; it < KNB; ++it) {
        unsigned long long best = ~0ull;
        #pragma unroll
        for (int s = 0; s < 4; ++s) {
            unsigned u = __float_as_uint(dist[s]);
            u = (u & 0x80000000u) ? ~u : (u | 0x80000000u);
            unsigned long long key = ((unsigned long long)u << 32) |
                                     (unsigned)(lane + 64 * s);
            if (key < best) best = key;
        }
        #pragma unroll
        for (int off = 32; off; off >>= 1) {
            unsigned long long o = __shfl_xor(best, off, 64);
            if (o < best) best = o;
        }
        int widx = (int)(best & 0xffffffffu);
        if (lane == (widx & 63)) dist[widx >> 6] = __uint_as_float(0x7f800000u);
        if (lane == 0) nbr[(size_t)rowid * KNB + it] = widx;
    }
}

// ------- compose: k-predictor collapse (f64) + inout@upd_w_top composition (f64) -------
__global__ __launch_bounds__(256) void compose_all(const float* __restrict__ kp_w,
        const float* __restrict__ kp_b, const float* __restrict__ enc_w,
        const float* __restrict__ enc_b, const float* __restrict__ mu_w,
        const float* __restrict__ mu_b, const float* __restrict__ dec_w,
        const float* __restrict__ dec_b, const float* __restrict__ inout_w,
        const float* __restrict__ inout_b, const float* __restrict__ upd_w,
        const float* __restrict__ upd_b,
        float* __restrict__ KW1, float* __restrict__ kb1,
        float* __restrict__ KW2, float* __restrict__ kb2,
        __bf16* __restrict__ updC, float* __restrict__ bcomp) {
    int bid = blockIdx.x;
    if (bid < 64) {
        int i = bid * 4 + (threadIdx.x >> 6);
        int j = threadIdx.x & 63;
        double acc = 0.0;
        for (int k = 0; k < 500; ++k)
            acc += (double)kp_w[(size_t)i * 500 + k] * (double)enc_w[(size_t)k * 64 + j];
        KW1[i * 64 + j] = (float)acc;
    } else if (bid == 64) {
        int j = threadIdx.x;
        if (j < 64) {
            double acc = (double)enc_b[j];
            for (int k = 0; k < 500; ++k)
                acc += (double)kp_b[k] * (double)enc_w[(size_t)k * 64 + j];
            kb1[j] = (float)acc;
        }
    } else if (bid < 68) {
        int t = (bid - 65) * 256 + threadIdx.x;
        if (t < 576) {
            int i = t / 9, j = t - (t / 9) * 9;
            double acc = 0.0;
            for (int k = 0; k < 32; ++k)
                acc += (double)mu_w[(size_t)i * 32 + k] * (double)dec_w[(size_t)k * 9 + j];
            KW2[t] = (float)acc;
        } else if (t < 585) {
            int j = t - 576;
            double acc = (double)dec_b[j];
            for (int k = 0; k < 32; ++k)
                acc += (double)mu_b[k] * (double)dec_w[(size_t)k * 9 + j];
            kb2[j] = (float)acc;
        }
    } else if (bid < 580) {
        // updC[n][k] for k<256: (inout_w @ upd_w[0:512])[k][n], f64 accum
        int e = (bid - 68) * 256 + threadIdx.x;     // 0..131071
        int k = e >> 9, n = e & 511;
        double acc = 0.0;
        for (int j = 0; j < 512; ++j)
            acc += (double)inout_w[(size_t)k * 512 + j] * (double)upd_w[(size_t)j * 512 + n];
        updC[(size_t)n * 768 + k] = (__bf16)(float)acc;
    } else {
        // bcomp[n] = inout_b @ upd_w[0:512] + upd_b
        int n = (bid - 580) * 256 + threadIdx.x;    // 0..511
        double acc = (double)upd_b[n];
        for (int j = 0; j < 512; ++j)
            acc += (double)inout_b[j] * (double)upd_w[(size_t)j * 512 + n];
        bcomp[n] = (float)acc;
    }
}

// ---------------- collapsed k-predictor ----------------
__global__ __launch_bounds__(256) void kint2_kernel(const float* __restrict__ x,
    const float* __restrict__ W1, const float* __restrict__ b1,
    const float* __restrict__ W2, const float* __restrict__ b2,
    int* __restrict__ kint, float* __restrict__ degf) {
    __shared__ __attribute__((aligned(16))) float xr[16][256];
    __shared__ float ebuf[16][64];
    __shared__ float lg[16][9];
    int t = threadIdx.x;
    int r0 = blockIdx.x * 16;
    const float4* xg = (const float4*)(x + (size_t)r0 * 256);
    float4* xs = (float4*)&xr[0][0];
    #pragma unroll
    for (int s = 0; s < 4; ++s) xs[s * 256 + t] = xg[s * 256 + t];
    __syncthreads();
    int w = t >> 6, l = t & 63;
    {
        float bb = b1[l];
        float a0 = bb, a1 = bb, a2 = bb, a3 = bb;
        const float* x0 = xr[w * 4 + 0];
        const float* x1 = xr[w * 4 + 1];
        const float* x2 = xr[w * 4 + 2];
        const float* x3 = xr[w * 4 + 3];
        for (int c = 0; c < 256; ++c) {
            float wv = W1[c * 64 + l];
            a0 = fmaf(x0[c], wv, a0);
            a1 = fmaf(x1[c], wv, a1);
            a2 = fmaf(x2[c], wv, a2);
            a3 = fmaf(x3[c], wv, a3);
        }
        ebuf[w * 4 + 0][l] = fmaxf(a0, 0.f);
        ebuf[w * 4 + 1][l] = fmaxf(a1, 0.f);
        ebuf[w * 4 + 2][l] = fmaxf(a2, 0.f);
        ebuf[w * 4 + 3][l] = fmaxf(a3, 0.f);
    }
    __syncthreads();
    int rr = t >> 4, cc = t & 15;
    if (cc < 9) {
        float acc = b2[cc];
        for (int j = 0; j < 64; ++j)
            acc = fmaf(ebuf[rr][j], W2[j * 9 + cc], acc);
        lg[rr][cc] = acc;
    }
    __syncthreads();
    if (cc == 0) {
        float best = lg[rr][0];
        int bi = 0;
        #pragma unroll
        for (int j = 1; j < 9; ++j)
            if (lg[rr][j] > best) { best = lg[rr][j]; bi = j; }
        kint[r0 + rr] = bi;
        degf[r0 + rr] = (float)bi;
    }
}

// ------- combine: H[r] = (relu?)( deg*(Pa[self]+bias) + sum_nbr Pb ) -------
// P rows are [Pa(256) | Pb(256)]. STAGE 1: P indexed over ROWS (shared x rows);
// STAGE 2: P indexed over 2*ROWS (branch-specific).
template<int STAGE, int RELU>
__global__ __launch_bounds__(256) void combine_kernel(const __bf16* __restrict__ P,
        const int* __restrict__ nbr, const int* __restrict__ kint_,
        const float* __restrict__ degf, const float* __restrict__ bias,
        __bf16* __restrict__ H) {
    int g = threadIdx.x >> 6, lane = threadIdx.x & 63;
    int r = blockIdx.x * 4 + g;                 // 0..2*ROWS
    int branch = (r >= ROWS);
    int rr = r - branch * ROWS;
    int b = rr / NPT, i = rr - b * NPT;
    size_t srow, mbase;
    if constexpr (STAGE == 1) {
        int fb = branch ? src_batch(b) : b;
        srow = (size_t)fb * NPT + i;
        mbase = (size_t)fb * NPT;
    } else {
        srow = (size_t)r;
        mbase = (size_t)branch * ROWS + (size_t)b * NPT;
    }
    const int* nb = nbr + (size_t)branch * ((size_t)ROWS * KNB) + (size_t)rr * KNB;
    bf16x4 sv = *(const bf16x4*)(P + srow * 512 + lane * 4);
    float4 bv = *(const float4*)(bias + lane * 4);
    float s0 = 0.f, s1 = 0.f, s2 = 0.f, s3 = 0.f;
    int kk = kint_[rr];
    for (int tt = 0; tt < kk; ++tt) {
        int m = nb[tt];
        bf16x4 v = *(const bf16x4*)(P + (mbase + m) * 512 + 256 + lane * 4);
        s0 += (float)v[0]; s1 += (float)v[1]; s2 += (float)v[2]; s3 += (float)v[3];
    }
    float dg = degf[rr];
    float o0 = fmaf(dg, (float)sv[0] + bv.x, s0);
    float o1 = fmaf(dg, (float)sv[1] + bv.y, s1);
    float o2 = fmaf(dg, (float)sv[2] + bv.z, s2);
    float o3 = fmaf(dg, (float)sv[3] + bv.w, s3);
    if constexpr (RELU) {
        o0 = fmaxf(o0, 0.f); o1 = fmaxf(o1, 0.f);
        o2 = fmaxf(o2, 0.f); o3 = fmaxf(o3, 0.f);
    }
    bf16x4 ov;
    ov[0] = (__bf16)o0; ov[1] = (__bf16)o1; ov[2] = (__bf16)o2; ov[3] = (__bf16)o3;
    *(bf16x4*)(H + (size_t)r * 256 + lane * 4) = ov;
}

// ---------------- bf16 MFMA GEMM ----------------
// FLAGS: 1=RELU, 4=bf16 out, 8=transposed out[b][c][i]. bias may be nullptr.
// CONCAT: A row = [A0 row (256) | A1 row (512)], K=768.
template<int FLAGS, int CONCAT>
__global__ __launch_bounds__(256) void mfma_gemm(
    const __bf16* __restrict__ A0, const __bf16* __restrict__ A1,
    const __bf16* __restrict__ WT, const float* __restrict__ bias,
    float* __restrict__ Cf, __bf16* __restrict__ Cb, int K, int N) {
    constexpr int SMEMB = (FLAGS & 8) ? (128 * 129 * 4) : (2 * 128 * 64 * 2);
    __shared__ __attribute__((aligned(16))) char smem[SMEMB];
    __bf16* As = (__bf16*)smem;
    __bf16* Bs = As + 128 * 64;
    int t = threadIdx.x, w = t >> 6, l = t & 63;
    int r0 = blockIdx.y * 128, c0 = blockIdx.x * 128;
    int lr = l & 15, lg = l >> 4;
    int wr = (w >> 1) * 64, wc = (w & 1) * 64;
    f32x4 acc[4][4] = {};
    for (int k0 = 0; k0 < K; k0 += 64) {
        const __bf16* Ab = A0;
        int kk = k0;
        size_t KA = (size_t)K;
        if constexpr (CONCAT) {
            if (k0 < 256) { Ab = A0; KA = 256; kk = k0; }
            else          { Ab = A1; KA = 512; kk = k0 - 256; }
        }
        #pragma unroll
        for (int i = 0; i < 4; ++i) {
            int row = (w * 4 + i) * 8 + (l >> 3);
            int c8 = l & 7;
            gload_lds16(Ab + (size_t)(r0 + row) * KA + kk + c8 * 8,
                        As + (w * 4 + i) * 512);
            gload_lds16(WT + (size_t)(c0 + row) * K + k0 + c8 * 8,
                        Bs + (w * 4 + i) * 512);
        }
        asm volatile("s_waitcnt vmcnt(0)" ::: "memory");
        __syncthreads();
        #pragma unroll
        for (int ks = 0; ks < 2; ++ks) {
            bf16x8 af[4], bfr[4];
            #pragma unroll
            for (int mi = 0; mi < 4; ++mi)
                af[mi] = *(const bf16x8*)(As + (wr + mi * 16 + lr) * 64 + ks * 32 + lg * 8);
            #pragma unroll
            for (int ni = 0; ni < 4; ++ni)
                bfr[ni] = *(const bf16x8*)(Bs + (wc + ni * 16 + lr) * 64 + ks * 32 + lg * 8);
            #pragma unroll
            for (int mi = 0; mi < 4; ++mi)
                #pragma unroll
                for (int ni = 0; ni < 4; ++ni)
                    acc[mi][ni] = __builtin_amdgcn_mfma_f32_16x16x32_bf16(
                        af[mi], bfr[ni], acc[mi][ni], 0, 0, 0);
        }
        __syncthreads();
    }
    if constexpr ((FLAGS & 8) != 0) {
        float* tile = (float*)smem;
        #pragma unroll
        for (int mi = 0; mi < 4; ++mi)
            #pragma unroll
            for (int r = 0; r < 4; ++r) {
                int rrow = wr + mi * 16 + lg * 4 + r;
                #pragma unroll
                for (int ni = 0; ni < 4; ++ni) {
                    int ccol = wc + ni * 16 + lr;
                    float v = acc[mi][ni][r];
                    if (bias) v += bias[c0 + ccol];
                    if constexpr ((FLAGS & 1) != 0) v = fmaxf(v, 0.f);
                    tile[rrow * 129 + ccol] = v;
                }
            }
        __syncthreads();
        int cc = t >> 6, rr2 = t & 63;
        #pragma unroll
        for (int cs = 0; cs < 128; cs += 4) {
            #pragma unroll
            for (int h = 0; h < 2; ++h) {
                int row = r0 + rr2 + h * 64;
                int bb = row / NPT, ii = row - bb * NPT;
                Cf[((size_t)bb * 512 + (c0 + cc + cs)) * NPT + ii] =
                    tile[(rr2 + h * 64) * 129 + cc + cs];
            }
        }
    } else {
        #pragma unroll
        for (int mi = 0; mi < 4; ++mi) {
            #pragma unroll
            for (int r = 0; r < 4; ++r) {
                int row = r0 + wr + mi * 16 + lg * 4 + r;
                #pragma unroll
                for (int ni = 0; ni < 4; ++ni) {
                    int col = c0 + wc + ni * 16 + lr;
                    float v = acc[mi][ni][r];
                    if (bias) v += bias[col];
                    if constexpr ((FLAGS & 1) != 0) v = fmaxf(v, 0.f);
                    if constexpr ((FLAGS & 4) != 0)
                        Cb[(size_t)row * N + col] = (__bf16)v;
                    else
                        Cf[(size_t)row * N + col] = v;
                }
            }
        }
    }
}

// ------- weight prep: W1cat/W2cat ([wa-wb | wb] transposed), fcet, updC bottom -------
__global__ __launch_bounds__(256) void transpose_all(
        const float* __restrict__ fc1_w, const float* __restrict__ fc2_w,
        const float* __restrict__ fce_w, const float* __restrict__ upd_w,
        __bf16* __restrict__ W1catT, __bf16* __restrict__ W2catT,
        __bf16* __restrict__ fcet, __bf16* __restrict__ updC) {
    __shared__ float tile[64][65];
    int bid = blockIdx.x;
    int t = threadIdx.x;
    if (bid < 64) {
        // W1catT/W2catT: [N=512][K=256]; n<256: w[k][n]-w[k+256][n]; n>=256: w[k+256][n-256]
        const float* W = (bid < 32) ? fc1_w : fc2_w;
        __bf16* WT = (bid < 32) ? W1catT : W2catT;
        int local = bid & 31;
        int n0 = (local >> 2) * 64, k0 = (local & 3) * 64;
        #pragma unroll
        for (int s = 0; s < 16; ++s) {
            int idx = s * 256 + t;
            int kk = idx >> 6, nn = idx & 63;
            float v;
            if (n0 < 256)
                v = W[(size_t)(k0 + kk) * 256 + n0 + nn] -
                    W[(size_t)(k0 + kk + 256) * 256 + n0 + nn];
            else
                v = W[(size_t)(k0 + kk + 256) * 256 + (n0 - 256) + nn];
            tile[kk][nn] = v;
        }
        __syncthreads();
        #pragma unroll
        for (int s = 0; s < 16; ++s) {
            int idx = s * 256 + t;
            int nn = idx >> 6, kk = idx & 63;
            WT[(size_t)(n0 + nn) * 256 + k0 + kk] = (__bf16)tile[kk][nn];
        }
    } else if (bid < 96) {
        // fcet[n*256+k] = fce_w[k*512+n], N=512, K=256
        int local = bid - 64;
        int n0 = (local >> 2) * 64, k0 = (local & 3) * 64;
        #pragma unroll
        for (int s = 0; s < 16; ++s) {
            int idx = s * 256 + t;
            int kk = idx >> 6, nn = idx & 63;
            tile[kk][nn] = fce_w[(size_t)(k0 + kk) * 512 + n0 + nn];
        }
        __syncthreads();
        #pragma unroll
        for (int s = 0; s < 16; ++s) {
            int idx = s * 256 + t;
            int nn = idx >> 6, kk = idx & 63;
            fcet[(size_t)(n0 + nn) * 256 + k0 + kk] = (__bf16)tile[kk][nn];
        }
    } else {
        // updC[n][256+k2] = upd_w[(512+k2)*512 + n], k2 in [0,512), n in [0,512)
        int local = bid - 96;                       // 0..63
        int k0 = (local >> 3) * 64, n0 = (local & 7) * 64;
        #pragma unroll
        for (int s = 0; s < 16; ++s) {
            int idx = s * 256 + t;
            int kk = idx >> 6, nn = idx & 63;
            tile[kk][nn] = upd_w[(size_t)(512 + k0 + kk) * 512 + n0 + nn];
        }
        __syncthreads();
        #pragma unroll
        for (int s = 0; s < 16; ++s) {
            int idx = s * 256 + t;
            int nn = idx >> 6, kk = idx & 63;
            updC[(size_t)(n0 + nn) * 768 + 256 + k0 + kk] = (__bf16)tile[kk][nn];
        }
    }
}

// ---------------- fused mix ----------------
__global__ __launch_bounds__(256) void fuse_mix(const float* __restrict__ XA,
        const float* __restrict__ YA, const float* __restrict__ wgt,
        __bf16* __restrict__ F) {
    int idx = blockIdx.x * 256 + threadIdx.x;
    size_t e0 = (size_t)idx * 4;
    int r = (int)(e0 >> 9);
    float wv = wgt[r];
    float4 xv = *(const float4*)(XA + e0);
    float4 yv = *(const float4*)(YA + e0);
    bf16x4 o;
    o[0] = (__bf16)(wv * xv.x + (1.f - wv) * yv.x);
    o[1] = (__bf16)(wv * xv.y + (1.f - wv) * yv.y);
    o[2] = (__bf16)(wv * xv.z + (1.f - wv) * yv.z);
    o[3] = (__bf16)(wv * xv.w + (1.f - wv) * yv.w);
    *(bf16x4*)(F + e0) = o;
}

// ---------------- attention scores ----------------
__global__ __launch_bounds__(256) void scores_kernel(const float* __restrict__ xagg,
        const float* __restrict__ yagg, const float* __restrict__ aw,
        const float* __restrict__ ab, float* __restrict__ scores) {
    int g = threadIdx.x >> 6, lane = threadIdx.x & 63;
    int r = blockIdx.x * 4 + g;
    float acc = 0.f;
    #pragma unroll
    for (int s = 0; s < 8; ++s) {
        int c = lane + 64 * s;
        acc = fmaf(xagg[(size_t)r * 512 + c], aw[c], acc);
        acc = fmaf(yagg[(size_t)r * 512 + c], aw[512 + c], acc);
    }
    #pragma unroll
    for (int off = 32; off; off >>= 1) acc += __shfl_xor(acc, off, 64);
    if (lane == 0) scores[r] = acc + ab[0];
}

// ---------------- global softmax ----------------
__global__ __launch_bounds__(1024) void softmax_kernel(const float* __restrict__ scores,
                                                       float* __restrict__ wgt) {
    __shared__ float red[1024];
    int t = threadIdx.x;
    float mx = -3.402823466e+38f;
    for (int i = t; i < ROWS; i += 1024) mx = fmaxf(mx, scores[i]);
    red[t] = mx; __syncthreads();
    for (int off = 512; off; off >>= 1) {
        if (t < off) red[t] = fmaxf(red[t], red[t + off]);
        __syncthreads();
    }
    mx = red[0]; __syncthreads();
    float sm = 0.f;
    for (int i = t; i < ROWS; i += 1024) sm += expf(scores[i] - mx);
    red[t] = sm; __syncthreads();
    for (int off = 512; off; off >>= 1) {
        if (t < off) red[t] += red[t + off];
        __syncthreads();
    }
    float denom = red[0];
    for (int i = t; i < ROWS; i += 1024) wgt[i] = expf(scores[i] - mx) / denom;
}

extern "C" void kernel_launch(void* const* d_in, const int* in_sizes, int n_in,
                              void* d_out, int out_size, void* d_ws, size_t ws_size,
                              hipStream_t stream) {
    (void)in_sizes; (void)n_in; (void)out_size; (void)ws_size;
    const float* x       = (const float*)d_in[0];
    const float* fc1_w   = (const float*)d_in[1];
    const float* fc1_b   = (const float*)d_in[2];
    const float* fc2_w   = (const float*)d_in[3];
    const float* fc2_b   = (const float*)d_in[4];
    const float* fce_w   = (const float*)d_in[5];
    const float* fce_b   = (const float*)d_in[6];
    const float* inout_w = (const float*)d_in[7];
    const float* inout_b = (const float*)d_in[8];
    const float* attn_w  = (const float*)d_in[9];
    const float* attn_b  = (const float*)d_in[10];
    const float* upd_w   = (const float*)d_in[11];
    const float* upd_b   = (const float*)d_in[12];
    const float* kp_w    = (const float*)d_in[13];
    const float* kp_b    = (const float*)d_in[14];
    const float* enc_w   = (const float*)d_in[15];
    const float* enc_b   = (const float*)d_in[16];
    const float* mu_w    = (const float*)d_in[17];
    const float* mu_b    = (const float*)d_in[18];
    const float* dec_w   = (const float*)d_in[19];
    const float* dec_b   = (const float*)d_in[20];
    float* out = (float*)d_out;

    char* base = (char*)d_ws;
    size_t o = 0;
    auto alloc = [&](size_t bytes) -> void* {
        void* p = base + o;
        o += (bytes + 255) & ~(size_t)255;
        return p;
    };
    float* qs     = (float*)alloc(ROWS * 4);
    float* degf   = (float*)alloc(ROWS * 4);
    float* scores = (float*)alloc(ROWS * 4);
    float* wgt    = (float*)alloc(ROWS * 4);
    int*   kint   = (int*)  alloc(ROWS * 4);
    float* KW1    = (float*)alloc(256 * 64 * 4);
    float* kb1    = (float*)alloc(64 * 4);
    float* KW2    = (float*)alloc(64 * 9 * 4);
    float* kb2    = (float*)alloc(9 * 4);
    float* bcomp  = (float*)alloc(512 * 4);
    int*   nbr    = (int*)  alloc((size_t)128 * NPT * KNB * 4);     //  0.80 MB
    char*  regD   = (char*) alloc((size_t)128 * NPT * NPT * 4);     // 19.66 MB
    __bf16* XB    = (__bf16*)alloc((size_t)ROWS * 256 * 2);         //  6.42 MB
    __bf16* H1    = (__bf16*)alloc((size_t)2 * ROWS * 256 * 2);     // 12.85 MB
    __bf16* H2    = (__bf16*)alloc((size_t)2 * ROWS * 256 * 2);     // 12.85 MB
    char*  regAGG = (char*) alloc((size_t)2 * ROWS * 512 * 4);      // 51.38 MB
    __bf16* W1catT= (__bf16*)alloc((size_t)512 * 256 * 2);
    __bf16* W2catT= (__bf16*)alloc((size_t)512 * 256 * 2);
    __bf16* fcet  = (__bf16*)alloc((size_t)512 * 256 * 2);
    __bf16* updC  = (__bf16*)alloc((size_t)512 * 768 * 2);
    // --- aliases (stream-order safe) ---
    float*  D     = (float*)regD;                  // dead after topk
    __bf16* P1buf = (__bf16*)regD;                 // stage-1 P (12.85MB), dead after combine1
    __bf16* FUSED = (__bf16*)regD;                 // written at step 15
    _Float16* XSPH = (_Float16*)regAGG;            // dead after gram
    _Float16* XSPL = XSPH + (size_t)64 * 256 * 256;
    __bf16* P2buf = (__bf16*)regAGG;               // stage-2 P (25.7MB), dead after combine2
    float*  AGG   = (float*)regAGG;                // written by fce after that
    float*  XAGG  = AGG;
    float*  YAGG  = AGG + (size_t)ROWS * 512;

    // ---- prep ----
    transpose_all<<<160, 256, 0, stream>>>(fc1_w, fc2_w, fce_w, upd_w,
                                           W1catT, W2catT, fcet, updC);
    compose_all<<<582, 256, 0, stream>>>(kp_w, kp_b, enc_w, enc_b,
                                         mu_w, mu_b, dec_w, dec_b,
                                         inout_w, inout_b, upd_w, upd_b,
                                         KW1, kb1, KW2, kb2, updC, bcomp);
    qs_kernel<<<64, 256, 0, stream>>>(x, qs);
    trans_split<<<dim3(4, 4, 64), 256, 0, stream>>>(x, XSPH, XSPL, XB);

    // ---- KNN + k-predictor ----
    gram_mfma<<<dim3(2, 2, 128), 256, 0, stream>>>(XSPH, XSPL, D);
    topk_kernel<<<(128 * NPT) / 4, 256, 0, stream>>>(D, qs, nbr);
    kint2_kernel<<<ROWS / 16, 256, 0, stream>>>(x, KW1, kb1, KW2, kb2, kint, degf);

    // ---- EdgeConv stage 1: project (ROWS only) then gather-combine ----
    mfma_gemm<4, 0><<<dim3(4, 98), 256, 0, stream>>>(
        XB, nullptr, W1catT, nullptr, nullptr, P1buf, 256, 512);
    combine_kernel<1, 1><<<2 * ROWS / 4, 256, 0, stream>>>(
        P1buf, nbr, kint, degf, fc1_b, H1);

    // ---- EdgeConv stage 2 ----
    mfma_gemm<4, 0><<<dim3(4, 196), 256, 0, stream>>>(
        H1, nullptr, W2catT, nullptr, nullptr, P2buf, 256, 512);
    combine_kernel<2, 0><<<2 * ROWS / 4, 256, 0, stream>>>(
        P2buf, nbr, kint, degf, fc2_b, H2);

    // ---- fce ----
    mfma_gemm<0, 0><<<dim3(4, 196), 256, 0, stream>>>(
        H2, nullptr, fcet, fce_b, AGG, nullptr, 256, 512);

    // ---- attention fusion ----
    scores_kernel<<<ROWS / 4, 256, 0, stream>>>(XAGG, YAGG, attn_w, attn_b, scores);
    softmax_kernel<<<1, 1024, 0, stream>>>(scores, wgt);
    fuse_mix<<<6272, 256, 0, stream>>>(XAGG, YAGG, wgt, FUSED);

    // ---- final fused upd GEMM (composed inout, K=768, transposed epilogue) ----
    mfma_gemm<9, 1><<<dim3(4, 98), 256, 0, stream>>>(
        XB, FUSED, updC, bcomp, out, nullptr, 768, 512);
}

// Round 7
// 259.330 us; speedup vs baseline: 1.0725x; 1.0725x over previous
//
#include <hip/hip_runtime.h>
#include <cstddef>
#include <cstdint>

constexpr int BATCH = 64;
constexpr int CH    = 256;
constexpr int NPT   = 196;
constexpr int ROWS  = BATCH * NPT;   // 12544
constexpr int BSTRIDE = CH * NPT;    // 50176
constexpr int KNB   = 8;             // position 8 (9th) is never valid: k_int <= 8

typedef __bf16 bf16x8 __attribute__((ext_vector_type(8)));
typedef __bf16 bf16x4 __attribute__((ext_vector_type(4)));
typedef _Float16 f16x8 __attribute__((ext_vector_type(8)));
typedef float  f32x4  __attribute__((ext_vector_type(4)));

__device__ __forceinline__ int src_batch(int b) {
    return (b & ~15) | ((b + 1) & 15);
}

__device__ __forceinline__ void gload_lds16(const void* g, void* l) {
    __builtin_amdgcn_global_load_lds(
        (const __attribute__((address_space(1))) void*)g,
        (__attribute__((address_space(3))) void*)l, 16, 0, 0);
}

// ---------------- qs: per-point squared norm (f32-exact) ----------------
__global__ __launch_bounds__(256) void qs_kernel(const float* __restrict__ x,
                                                 float* __restrict__ qs) {
    int b = blockIdx.x;
    int m = threadIdx.x;
    if (m >= NPT) return;
    const float* xb = x + (size_t)b * BSTRIDE;
    float acc = 0.f;
    for (int c = 0; c < CH; ++c) {
        float v = xb[c * NPT + m];
        acc = fmaf(v, v, acc);
    }
    qs[b * NPT + m] = acc;
}

// ------- transpose + f16 hi/lo split + bf16 copy -------
__global__ __launch_bounds__(256) void trans_split(const float* __restrict__ x,
        _Float16* __restrict__ XH, _Float16* __restrict__ XL,
        __bf16* __restrict__ XB) {
    __shared__ float tile[64][65];
    int b = blockIdx.z;
    int m0 = blockIdx.x * 64, c0 = blockIdx.y * 64;
    int t = threadIdx.x;
    const float* xb = x + (size_t)b * BSTRIDE;
    #pragma unroll
    for (int s = 0; s < 16; ++s) {
        int idx = s * 256 + t;
        int cc = idx >> 6, mm = idx & 63;
        int m = m0 + mm;
        float v = (m < NPT) ? xb[(size_t)(c0 + cc) * NPT + m] : 0.f;
        tile[cc][mm] = v;
        if (m < NPT)
            XB[(size_t)b * BSTRIDE + (size_t)(c0 + cc) * NPT + m] = (__bf16)v;
    }
    __syncthreads();
    #pragma unroll
    for (int s = 0; s < 16; ++s) {
        int idx = s * 256 + t;
        int mm = idx >> 6, cc = idx & 63;
        float v = tile[cc][mm];
        _Float16 h = (_Float16)v;
        size_t off = ((size_t)b * 256 + (m0 + mm)) * 256 + c0 + cc;
        XH[off] = h;
        XL[off] = (_Float16)(v - (float)h);
    }
}

// ---------------- Gram via f16-split MFMA ----------------
__global__ __launch_bounds__(256) void gram_mfma(const _Float16* __restrict__ XH,
        const _Float16* __restrict__ XL, float* __restrict__ D) {
    __shared__ __attribute__((aligned(16))) _Float16 Ah[128 * 64];
    __shared__ __attribute__((aligned(16))) _Float16 Al[128 * 64];
    __shared__ __attribute__((aligned(16))) _Float16 Bh[128 * 64];
    __shared__ __attribute__((aligned(16))) _Float16 Bl[128 * 64];
    int job = blockIdx.z;
    int qb = (job < 64) ? job : job - 64;
    int kb = (job < 64) ? qb : src_batch(qb);
    int t = threadIdx.x, w = t >> 6, l = t & 63;
    int r0 = blockIdx.y * 128, c0 = blockIdx.x * 128;
    int lr = l & 15, lg = l >> 4;
    int wr = (w >> 1) * 64, wc = (w & 1) * 64;
    const _Float16* qh = XH + (size_t)qb * 65536;
    const _Float16* ql = XL + (size_t)qb * 65536;
    const _Float16* kh = XH + (size_t)kb * 65536;
    const _Float16* kl = XL + (size_t)kb * 65536;
    f32x4 acc[4][4] = {};
    for (int k0 = 0; k0 < 256; k0 += 64) {
        #pragma unroll
        for (int i = 0; i < 4; ++i) {
            int row = (w * 4 + i) * 8 + (l >> 3);
            int c8 = l & 7;
            size_t goA = (size_t)(r0 + row) * 256 + k0 + c8 * 8;
            size_t goB = (size_t)(c0 + row) * 256 + k0 + c8 * 8;
            gload_lds16(qh + goA, Ah + (w * 4 + i) * 512);
            gload_lds16(ql + goA, Al + (w * 4 + i) * 512);
            gload_lds16(kh + goB, Bh + (w * 4 + i) * 512);
            gload_lds16(kl + goB, Bl + (w * 4 + i) * 512);
        }
        asm volatile("s_waitcnt vmcnt(0)" ::: "memory");
        __syncthreads();
        #pragma unroll
        for (int ks = 0; ks < 2; ++ks) {
            f16x8 ah[4], al[4], bh[4], bl[4];
            #pragma unroll
            for (int mi = 0; mi < 4; ++mi) {
                ah[mi] = *(const f16x8*)(Ah + (wr + mi * 16 + lr) * 64 + ks * 32 + lg * 8);
                al[mi] = *(const f16x8*)(Al + (wr + mi * 16 + lr) * 64 + ks * 32 + lg * 8);
            }
            #pragma unroll
            for (int ni = 0; ni < 4; ++ni) {
                bh[ni] = *(const f16x8*)(Bh + (wc + ni * 16 + lr) * 64 + ks * 32 + lg * 8);
                bl[ni] = *(const f16x8*)(Bl + (wc + ni * 16 + lr) * 64 + ks * 32 + lg * 8);
            }
            #pragma unroll
            for (int mi = 0; mi < 4; ++mi)
                #pragma unroll
                for (int ni = 0; ni < 4; ++ni) {
                    acc[mi][ni] = __builtin_amdgcn_mfma_f32_16x16x32_f16(
                        ah[mi], bh[ni], acc[mi][ni], 0, 0, 0);
                    acc[mi][ni] = __builtin_amdgcn_mfma_f32_16x16x32_f16(
                        ah[mi], bl[ni], acc[mi][ni], 0, 0, 0);
                    acc[mi][ni] = __builtin_amdgcn_mfma_f32_16x16x32_f16(
                        al[mi], bh[ni], acc[mi][ni], 0, 0, 0);
                }
        }
        __syncthreads();
    }
    #pragma unroll
    for (int mi = 0; mi < 4; ++mi) {
        #pragma unroll
        for (int r = 0; r < 4; ++r) {
            int gi = r0 + wr + mi * 16 + lg * 4 + r;
            if (gi >= NPT) continue;
            #pragma unroll
            for (int ni = 0; ni < 4; ++ni) {
                int gj = c0 + wc + ni * 16 + lr;
                if (gj < NPT)
                    D[(size_t)job * (NPT * NPT) + (size_t)gi * NPT + gj] =
                        acc[mi][ni][r];
            }
        }
    }
}

// ---------------- top-8 selection ----------------
__global__ __launch_bounds__(256) void topk_kernel(const float* __restrict__ D,
                                                   const float* __restrict__ qs,
                                                   int* __restrict__ nbr) {
    int wid = threadIdx.x >> 6;
    int lane = threadIdx.x & 63;
    int rowid = blockIdx.x * 4 + wid;
    int job = rowid / NPT;
    int i = rowid - job * NPT;
    int qb = (job < 64) ? job : job - 64;
    int kb = (job < 64) ? qb : src_batch(qb);
    const float* drow = D + (size_t)job * (NPT * NPT) + (size_t)i * NPT;
    float qsi = qs[qb * NPT + i];
    const float* ksr = qs + kb * NPT;
    float dist[4];
    #pragma unroll
    for (int s = 0; s < 4; ++s) {
        int m = lane + 64 * s;
        dist[s] = (m < NPT) ? (qsi - 2.f * drow[m] + ksr[m])
                            : __uint_as_float(0x7f800000u);
    }
    for (int it = 0; it < KNB; ++it) {
        unsigned long long best = ~0ull;
        #pragma unroll
        for (int s = 0; s < 4; ++s) {
            unsigned u = __float_as_uint(dist[s]);
            u = (u & 0x80000000u) ? ~u : (u | 0x80000000u);
            unsigned long long key = ((unsigned long long)u << 32) |
                                     (unsigned)(lane + 64 * s);
            if (key < best) best = key;
        }
        #pragma unroll
        for (int off = 32; off; off >>= 1) {
            unsigned long long o = __shfl_xor(best, off, 64);
            if (o < best) best = o;
        }
        int widx = (int)(best & 0xffffffffu);
        if (lane == (widx & 63)) dist[widx >> 6] = __uint_as_float(0x7f800000u);
        if (lane == 0) nbr[(size_t)rowid * KNB + it] = widx;
    }
}

// ------- compose: k-predictor collapse (f64) + inout@upd_w_top composition (f64) -------
__global__ __launch_bounds__(256) void compose_all(const float* __restrict__ kp_w,
        const float* __restrict__ kp_b, const float* __restrict__ enc_w,
        const float* __restrict__ enc_b, const float* __restrict__ mu_w,
        const float* __restrict__ mu_b, const float* __restrict__ dec_w,
        const float* __restrict__ dec_b, const float* __restrict__ inout_w,
        const float* __restrict__ inout_b, const float* __restrict__ upd_w,
        const float* __restrict__ upd_b,
        float* __restrict__ KW1, float* __restrict__ kb1,
        float* __restrict__ KW2, float* __restrict__ kb2,
        __bf16* __restrict__ updC, float* __restrict__ bcomp) {
    int bid = blockIdx.x;
    if (bid < 64) {
        int i = bid * 4 + (threadIdx.x >> 6);
        int j = threadIdx.x & 63;
        double acc = 0.0;
        for (int k = 0; k < 500; ++k)
            acc += (double)kp_w[(size_t)i * 500 + k] * (double)enc_w[(size_t)k * 64 + j];
        KW1[i * 64 + j] = (float)acc;
    } else if (bid == 64) {
        int j = threadIdx.x;
        if (j < 64) {
            double acc = (double)enc_b[j];
            for (int k = 0; k < 500; ++k)
                acc += (double)kp_b[k] * (double)enc_w[(size_t)k * 64 + j];
            kb1[j] = (float)acc;
        }
    } else if (bid < 68) {
        int t = (bid - 65) * 256 + threadIdx.x;
        if (t < 576) {
            int i = t / 9, j = t - (t / 9) * 9;
            double acc = 0.0;
            for (int k = 0; k < 32; ++k)
                acc += (double)mu_w[(size_t)i * 32 + k] * (double)dec_w[(size_t)k * 9 + j];
            KW2[t] = (float)acc;
        } else if (t < 585) {
            int j = t - 576;
            double acc = (double)dec_b[j];
            for (int k = 0; k < 32; ++k)
                acc += (double)mu_b[k] * (double)dec_w[(size_t)k * 9 + j];
            kb2[j] = (float)acc;
        }
    } else if (bid < 580) {
        int e = (bid - 68) * 256 + threadIdx.x;     // 0..131071
        int k = e >> 9, n = e & 511;
        double acc = 0.0;
        for (int j = 0; j < 512; ++j)
            acc += (double)inout_w[(size_t)k * 512 + j] * (double)upd_w[(size_t)j * 512 + n];
        updC[(size_t)n * 768 + k] = (__bf16)(float)acc;
    } else {
        int n = (bid - 580) * 256 + threadIdx.x;    // 0..511
        double acc = (double)upd_b[n];
        for (int j = 0; j < 512; ++j)
            acc += (double)inout_b[j] * (double)upd_w[(size_t)j * 512 + n];
        bcomp[n] = (float)acc;
    }
}

// ---------------- collapsed k-predictor ----------------
__global__ __launch_bounds__(256) void kint2_kernel(const float* __restrict__ x,
    const float* __restrict__ W1, const float* __restrict__ b1,
    const float* __restrict__ W2, const float* __restrict__ b2,
    int* __restrict__ kint, float* __restrict__ degf) {
    __shared__ __attribute__((aligned(16))) float xr[16][256];
    __shared__ float ebuf[16][64];
    __shared__ float lg[16][9];
    int t = threadIdx.x;
    int r0 = blockIdx.x * 16;
    const float4* xg = (const float4*)(x + (size_t)r0 * 256);
    float4* xs = (float4*)&xr[0][0];
    #pragma unroll
    for (int s = 0; s < 4; ++s) xs[s * 256 + t] = xg[s * 256 + t];
    __syncthreads();
    int w = t >> 6, l = t & 63;
    {
        float bb = b1[l];
        float a0 = bb, a1 = bb, a2 = bb, a3 = bb;
        const float* x0 = xr[w * 4 + 0];
        const float* x1 = xr[w * 4 + 1];
        const float* x2 = xr[w * 4 + 2];
        const float* x3 = xr[w * 4 + 3];
        for (int c = 0; c < 256; ++c) {
            float wv = W1[c * 64 + l];
            a0 = fmaf(x0[c], wv, a0);
            a1 = fmaf(x1[c], wv, a1);
            a2 = fmaf(x2[c], wv, a2);
            a3 = fmaf(x3[c], wv, a3);
        }
        ebuf[w * 4 + 0][l] = fmaxf(a0, 0.f);
        ebuf[w * 4 + 1][l] = fmaxf(a1, 0.f);
        ebuf[w * 4 + 2][l] = fmaxf(a2, 0.f);
        ebuf[w * 4 + 3][l] = fmaxf(a3, 0.f);
    }
    __syncthreads();
    int rr = t >> 4, cc = t & 15;
    if (cc < 9) {
        float acc = b2[cc];
        for (int j = 0; j < 64; ++j)
            acc = fmaf(ebuf[rr][j], W2[j * 9 + cc], acc);
        lg[rr][cc] = acc;
    }
    __syncthreads();
    if (cc == 0) {
        float best = lg[rr][0];
        int bi = 0;
        #pragma unroll
        for (int j = 1; j < 9; ++j)
            if (lg[rr][j] > best) { best = lg[rr][j]; bi = j; }
        kint[r0 + rr] = bi;
        degf[r0 + rr] = (float)bi;
    }
}

// ------- combine: H[r] = (relu?)( deg*(Pa[self]+bias) + sum_nbr Pb ) -------
template<int STAGE, int RELU>
__global__ __launch_bounds__(256) void combine_kernel(const __bf16* __restrict__ P,
        const int* __restrict__ nbr, const int* __restrict__ kint_,
        const float* __restrict__ degf, const float* __restrict__ bias,
        __bf16* __restrict__ H) {
    int g = threadIdx.x >> 6, lane = threadIdx.x & 63;
    int r = blockIdx.x * 4 + g;                 // 0..2*ROWS
    int branch = (r >= ROWS);
    int rr = r - branch * ROWS;
    int b = rr / NPT, i = rr - b * NPT;
    size_t srow, mbase;
    if constexpr (STAGE == 1) {
        int fb = branch ? src_batch(b) : b;
        srow = (size_t)fb * NPT + i;
        mbase = (size_t)fb * NPT;
    } else {
        srow = (size_t)r;
        mbase = (size_t)branch * ROWS + (size_t)b * NPT;
    }
    const int* nb = nbr + (size_t)branch * ((size_t)ROWS * KNB) + (size_t)rr * KNB;
    bf16x4 sv = *(const bf16x4*)(P + srow * 512 + lane * 4);
    float4 bv = *(const float4*)(bias + lane * 4);
    float s0 = 0.f, s1 = 0.f, s2 = 0.f, s3 = 0.f;
    int kk = kint_[rr];
    for (int tt = 0; tt < kk; ++tt) {
        int m = nb[tt];
        bf16x4 v = *(const bf16x4*)(P + (mbase + m) * 512 + 256 + lane * 4);
        s0 += (float)v[0]; s1 += (float)v[1]; s2 += (float)v[2]; s3 += (float)v[3];
    }
    float dg = degf[rr];
    float o0 = fmaf(dg, (float)sv[0] + bv.x, s0);
    float o1 = fmaf(dg, (float)sv[1] + bv.y, s1);
    float o2 = fmaf(dg, (float)sv[2] + bv.z, s2);
    float o3 = fmaf(dg, (float)sv[3] + bv.w, s3);
    if constexpr (RELU) {
        o0 = fmaxf(o0, 0.f); o1 = fmaxf(o1, 0.f);
        o2 = fmaxf(o2, 0.f); o3 = fmaxf(o3, 0.f);
    }
    bf16x4 ov;
    ov[0] = (__bf16)o0; ov[1] = (__bf16)o1; ov[2] = (__bf16)o2; ov[3] = (__bf16)o3;
    *(bf16x4*)(H + (size_t)r * 256 + lane * 4) = ov;
}

// ---------------- bf16 MFMA GEMM ----------------
// FLAGS: 1=RELU, 4=bf16 out, 8=transposed out[b][c][i], 16=scores epilogue (implies bf16 out).
// CONCAT: 0 plain; 2 = A row = [A0(256) | wgt-mix of A1/A1+ROWS*512 (512)], K=768.
template<int FLAGS, int CONCAT>
__global__ __launch_bounds__(256) void mfma_gemm(
    const __bf16* __restrict__ A0, const __bf16* __restrict__ A1,
    const __bf16* __restrict__ WT, const float* __restrict__ bias,
    float* __restrict__ Cf, __bf16* __restrict__ Cb, int K, int N,
    const float* __restrict__ aw, float* __restrict__ scp,
    const float* __restrict__ wgt) {
    constexpr int SMEMB = (FLAGS & 8) ? (128 * 129 * 4) : (2 * 128 * 64 * 2);
    __shared__ __attribute__((aligned(16))) char smem[SMEMB];
    __bf16* As = (__bf16*)smem;
    __bf16* Bs = As + 128 * 64;
    int t = threadIdx.x, w = t >> 6, l = t & 63;
    int r0 = blockIdx.y * 128, c0 = blockIdx.x * 128;
    int lr = l & 15, lg = l >> 4;
    int wr = (w >> 1) * 64, wc = (w & 1) * 64;
    f32x4 acc[4][4] = {};
    for (int k0 = 0; k0 < K; k0 += 64) {
        #pragma unroll
        for (int i = 0; i < 4; ++i) {
            int row = (w * 4 + i) * 8 + (l >> 3);
            int c8 = l & 7;
            if constexpr (CONCAT == 2) {
                if (k0 < 256) {
                    gload_lds16(A0 + (size_t)(r0 + row) * 256 + k0 + c8 * 8,
                                As + (w * 4 + i) * 512);
                } else {
                    int kk2 = k0 - 256 + c8 * 8;
                    size_t gr = (size_t)(r0 + row);
                    bf16x8 xa = *(const bf16x8*)(A1 + gr * 512 + kk2);
                    bf16x8 ya = *(const bf16x8*)(A1 + ((size_t)ROWS + gr) * 512 + kk2);
                    float wv = wgt[gr];
                    bf16x8 mx;
                    #pragma unroll
                    for (int j = 0; j < 8; ++j)
                        mx[j] = (__bf16)(wv * (float)xa[j] + (1.f - wv) * (float)ya[j]);
                    *(bf16x8*)(As + (w * 4 + i) * 512 + l * 8) = mx;
                }
            } else {
                gload_lds16(A0 + (size_t)(r0 + row) * K + k0 + c8 * 8,
                            As + (w * 4 + i) * 512);
            }
            gload_lds16(WT + (size_t)(c0 + row) * K + k0 + c8 * 8,
                        Bs + (w * 4 + i) * 512);
        }
        asm volatile("s_waitcnt vmcnt(0)" ::: "memory");
        __syncthreads();
        #pragma unroll
        for (int ks = 0; ks < 2; ++ks) {
            bf16x8 af[4], bfr[4];
            #pragma unroll
            for (int mi = 0; mi < 4; ++mi)
                af[mi] = *(const bf16x8*)(As + (wr + mi * 16 + lr) * 64 + ks * 32 + lg * 8);
            #pragma unroll
            for (int ni = 0; ni < 4; ++ni)
                bfr[ni] = *(const bf16x8*)(Bs + (wc + ni * 16 + lr) * 64 + ks * 32 + lg * 8);
            #pragma unroll
            for (int mi = 0; mi < 4; ++mi)
                #pragma unroll
                for (int ni = 0; ni < 4; ++ni)
                    acc[mi][ni] = __builtin_amdgcn_mfma_f32_16x16x32_bf16(
                        af[mi], bfr[ni], acc[mi][ni], 0, 0, 0);
        }
        __syncthreads();
    }
    if constexpr ((FLAGS & 8) != 0) {
        float* tile = (float*)smem;
        #pragma unroll
        for (int mi = 0; mi < 4; ++mi)
            #pragma unroll
            for (int r = 0; r < 4; ++r) {
                int rrow = wr + mi * 16 + lg * 4 + r;
                #pragma unroll
                for (int ni = 0; ni < 4; ++ni) {
                    int ccol = wc + ni * 16 + lr;
                    float v = acc[mi][ni][r];
                    if (bias) v += bias[c0 + ccol];
                    if constexpr ((FLAGS & 1) != 0) v = fmaxf(v, 0.f);
                    tile[rrow * 129 + ccol] = v;
                }
            }
        __syncthreads();
        int cc = t >> 6, rr2 = t & 63;
        #pragma unroll
        for (int cs = 0; cs < 128; cs += 4) {
            #pragma unroll
            for (int h = 0; h < 2; ++h) {
                int row = r0 + rr2 + h * 64;
                int bb = row / NPT, ii = row - bb * NPT;
                Cf[((size_t)bb * 512 + (c0 + cc + cs)) * NPT + ii] =
                    tile[(rr2 + h * 64) * 129 + cc + cs];
            }
        }
    } else if constexpr ((FLAGS & 16) != 0) {
        // bf16 store + fused attention-score partial (deterministic)
        int half = (r0 >= ROWS) ? 1 : 0;
        float ps[4][4] = {};
        #pragma unroll
        for (int mi = 0; mi < 4; ++mi)
            #pragma unroll
            for (int r = 0; r < 4; ++r) {
                int row = r0 + wr + mi * 16 + lg * 4 + r;
                #pragma unroll
                for (int ni = 0; ni < 4; ++ni) {
                    int col = c0 + wc + ni * 16 + lr;
                    float v = acc[mi][ni][r] + bias[col];
                    Cb[(size_t)row * N + col] = (__bf16)v;
                    ps[mi][r] = fmaf(v, aw[half * 512 + col], ps[mi][r]);
                }
            }
        #pragma unroll
        for (int m = 1; m <= 8; m <<= 1)
            #pragma unroll
            for (int mi = 0; mi < 4; ++mi)
                #pragma unroll
                for (int r = 0; r < 4; ++r)
                    ps[mi][r] += __shfl_xor(ps[mi][r], m, 64);
        if (lr == 0) {
            int slot = half * 8 + blockIdx.x * 2 + (w & 1);
            #pragma unroll
            for (int mi = 0; mi < 4; ++mi)
                #pragma unroll
                for (int r = 0; r < 4; ++r) {
                    int sr = r0 - half * ROWS + wr + mi * 16 + lg * 4 + r;
                    scp[(size_t)slot * ROWS + sr] = ps[mi][r];
                }
        }
    } else {
        #pragma unroll
        for (int mi = 0; mi < 4; ++mi) {
            #pragma unroll
            for (int r = 0; r < 4; ++r) {
                int row = r0 + wr + mi * 16 + lg * 4 + r;
                #pragma unroll
                for (int ni = 0; ni < 4; ++ni) {
                    int col = c0 + wc + ni * 16 + lr;
                    float v = acc[mi][ni][r];
                    if (bias) v += bias[col];
                    if constexpr ((FLAGS & 1) != 0) v = fmaxf(v, 0.f);
                    if constexpr ((FLAGS & 4) != 0)
                        Cb[(size_t)row * N + col] = (__bf16)v;
                    else
                        Cf[(size_t)row * N + col] = v;
                }
            }
        }
    }
}

// ------- weight prep -------
__global__ __launch_bounds__(256) void transpose_all(
        const float* __restrict__ fc1_w, const float* __restrict__ fc2_w,
        const float* __restrict__ fce_w, const float* __restrict__ upd_w,
        __bf16* __restrict__ W1catT, __bf16* __restrict__ W2catT,
        __bf16* __restrict__ fcet, __bf16* __restrict__ updC) {
    __shared__ float tile[64][65];
    int bid = blockIdx.x;
    int t = threadIdx.x;
    if (bid < 64) {
        const float* W = (bid < 32) ? fc1_w : fc2_w;
        __bf16* WT = (bid < 32) ? W1catT : W2catT;
        int local = bid & 31;
        int n0 = (local >> 2) * 64, k0 = (local & 3) * 64;
        #pragma unroll
        for (int s = 0; s < 16; ++s) {
            int idx = s * 256 + t;
            int kk = idx >> 6, nn = idx & 63;
            float v;
            if (n0 < 256)
                v = W[(size_t)(k0 + kk) * 256 + n0 + nn] -
                    W[(size_t)(k0 + kk + 256) * 256 + n0 + nn];
            else
                v = W[(size_t)(k0 + kk + 256) * 256 + (n0 - 256) + nn];
            tile[kk][nn] = v;
        }
        __syncthreads();
        #pragma unroll
        for (int s = 0; s < 16; ++s) {
            int idx = s * 256 + t;
            int nn = idx >> 6, kk = idx & 63;
            WT[(size_t)(n0 + nn) * 256 + k0 + kk] = (__bf16)tile[kk][nn];
        }
    } else if (bid < 96) {
        int local = bid - 64;
        int n0 = (local >> 2) * 64, k0 = (local & 3) * 64;
        #pragma unroll
        for (int s = 0; s < 16; ++s) {
            int idx = s * 256 + t;
            int kk = idx >> 6, nn = idx & 63;
            tile[kk][nn] = fce_w[(size_t)(k0 + kk) * 512 + n0 + nn];
        }
        __syncthreads();
        #pragma unroll
        for (int s = 0; s < 16; ++s) {
            int idx = s * 256 + t;
            int nn = idx >> 6, kk = idx & 63;
            fcet[(size_t)(n0 + nn) * 256 + k0 + kk] = (__bf16)tile[kk][nn];
        }
    } else {
        int local = bid - 96;                       // 0..63
        int k0 = (local >> 3) * 64, n0 = (local & 7) * 64;
        #pragma unroll
        for (int s = 0; s < 16; ++s) {
            int idx = s * 256 + t;
            int kk = idx >> 6, nn = idx & 63;
            tile[kk][nn] = upd_w[(size_t)(512 + k0 + kk) * 512 + n0 + nn];
        }
        __syncthreads();
        #pragma unroll
        for (int s = 0; s < 16; ++s) {
            int idx = s * 256 + t;
            int nn = idx >> 6, kk = idx & 63;
            updC[(size_t)(n0 + nn) * 768 + 256 + k0 + kk] = (__bf16)tile[kk][nn];
        }
    }
}

// ------- softmax stage 1: sum 16 deterministic partials -> score; block max/sumexp -------
__global__ __launch_bounds__(256) void softmax_part(const float* __restrict__ scp,
        const float* __restrict__ ab, float* __restrict__ scores,
        float* __restrict__ mpart, float* __restrict__ spart) {
    __shared__ float red[256];
    int t = threadIdx.x;
    int sr = blockIdx.x * 256 + t;              // 49*256 = ROWS exactly
    float s = ab[0];
    #pragma unroll
    for (int i = 0; i < 16; ++i) s += scp[(size_t)i * ROWS + sr];
    scores[sr] = s;
    red[t] = s; __syncthreads();
    for (int off = 128; off; off >>= 1) {
        if (t < off) red[t] = fmaxf(red[t], red[t + off]);
        __syncthreads();
    }
    float mb = red[0]; __syncthreads();
    red[t] = expf(s - mb); __syncthreads();
    for (int off = 128; off; off >>= 1) {
        if (t < off) red[t] += red[t + off];
        __syncthreads();
    }
    if (t == 0) { mpart[blockIdx.x] = mb; spart[blockIdx.x] = red[0]; }
}

// ------- softmax stage 2: combine 49 partials, write wgt -------
__global__ __launch_bounds__(256) void softmax_fin(const float* __restrict__ mpart,
        const float* __restrict__ spart, const float* __restrict__ scores,
        float* __restrict__ wgt) {
    __shared__ float MS[2];
    if (threadIdx.x == 0) {
        float M = mpart[0];
        for (int i = 1; i < 49; ++i) M = fmaxf(M, mpart[i]);
        float S = 0.f;
        for (int i = 0; i < 49; ++i) S += spart[i] * expf(mpart[i] - M);
        MS[0] = M; MS[1] = S;
    }
    __syncthreads();
    float M = MS[0], denom = MS[1];
    for (int i = threadIdx.x; i < ROWS; i += 256)
        wgt[i] = expf(scores[i] - M) / denom;
}

extern "C" void kernel_launch(void* const* d_in, const int* in_sizes, int n_in,
                              void* d_out, int out_size, void* d_ws, size_t ws_size,
                              hipStream_t stream) {
    (void)in_sizes; (void)n_in; (void)out_size; (void)ws_size;
    const float* x       = (const float*)d_in[0];
    const float* fc1_w   = (const float*)d_in[1];
    const float* fc1_b   = (const float*)d_in[2];
    const float* fc2_w   = (const float*)d_in[3];
    const float* fc2_b   = (const float*)d_in[4];
    const float* fce_w   = (const float*)d_in[5];
    const float* fce_b   = (const float*)d_in[6];
    const float* inout_w = (const float*)d_in[7];
    const float* inout_b = (const float*)d_in[8];
    const float* attn_w  = (const float*)d_in[9];
    const float* attn_b  = (const float*)d_in[10];
    const float* upd_w   = (const float*)d_in[11];
    const float* upd_b   = (const float*)d_in[12];
    const float* kp_w    = (const float*)d_in[13];
    const float* kp_b    = (const float*)d_in[14];
    const float* enc_w   = (const float*)d_in[15];
    const float* enc_b   = (const float*)d_in[16];
    const float* mu_w    = (const float*)d_in[17];
    const float* mu_b    = (const float*)d_in[18];
    const float* dec_w   = (const float*)d_in[19];
    const float* dec_b   = (const float*)d_in[20];
    float* out = (float*)d_out;

    char* base = (char*)d_ws;
    size_t o = 0;
    auto alloc = [&](size_t bytes) -> void* {
        void* p = base + o;
        o += (bytes + 255) & ~(size_t)255;
        return p;
    };
    float* qs     = (float*)alloc(ROWS * 4);
    float* degf   = (float*)alloc(ROWS * 4);
    float* scores = (float*)alloc(ROWS * 4);
    float* wgt    = (float*)alloc(ROWS * 4);
    int*   kint   = (int*)  alloc(ROWS * 4);
    float* KW1    = (float*)alloc(256 * 64 * 4);
    float* kb1    = (float*)alloc(64 * 4);
    float* KW2    = (float*)alloc(64 * 9 * 4);
    float* kb2    = (float*)alloc(9 * 4);
    float* bcomp  = (float*)alloc(512 * 4);
    float* scp    = (float*)alloc((size_t)16 * ROWS * 4);           //  0.80 MB
    float* mpart  = (float*)alloc(64 * 4);
    float* spart  = (float*)alloc(64 * 4);
    int*   nbr    = (int*)  alloc((size_t)128 * NPT * KNB * 4);     //  0.80 MB
    char*  regD   = (char*) alloc((size_t)128 * NPT * NPT * 4);     // 19.66 MB
    __bf16* XB    = (__bf16*)alloc((size_t)ROWS * 256 * 2);         //  6.42 MB
    __bf16* H1    = (__bf16*)alloc((size_t)2 * ROWS * 256 * 2);     // 12.85 MB
    __bf16* H2    = (__bf16*)alloc((size_t)2 * ROWS * 256 * 2);     // 12.85 MB
    char*  regAGG = (char*) alloc((size_t)2 * ROWS * 512 * 4);      // 51.38 MB
    __bf16* W1catT= (__bf16*)alloc((size_t)512 * 256 * 2);
    __bf16* W2catT= (__bf16*)alloc((size_t)512 * 256 * 2);
    __bf16* fcet  = (__bf16*)alloc((size_t)512 * 256 * 2);
    __bf16* updC  = (__bf16*)alloc((size_t)512 * 768 * 2);
    // --- aliases (stream-order safe) ---
    float*  D     = (float*)regD;                  // dead after topk
    __bf16* P1buf = (__bf16*)regD;                 // stage-1 P, dead after combine1
    _Float16* XSPH = (_Float16*)regAGG;            // dead after gram
    _Float16* XSPL = XSPH + (size_t)64 * 256 * 256;
    __bf16* P2buf = (__bf16*)regAGG;               // stage-2 P, dead after combine2
    __bf16* AGGb  = (__bf16*)regAGG;               // fce output (bf16), 25.7 MB
    __bf16* XAGGb = AGGb;
    // YAGGb = AGGb + ROWS*512 (implicit in CONCAT==2 path)

    // ---- prep ----
    transpose_all<<<160, 256, 0, stream>>>(fc1_w, fc2_w, fce_w, upd_w,
                                           W1catT, W2catT, fcet, updC);
    compose_all<<<582, 256, 0, stream>>>(kp_w, kp_b, enc_w, enc_b,
                                         mu_w, mu_b, dec_w, dec_b,
                                         inout_w, inout_b, upd_w, upd_b,
                                         KW1, kb1, KW2, kb2, updC, bcomp);
    qs_kernel<<<64, 256, 0, stream>>>(x, qs);
    trans_split<<<dim3(4, 4, 64), 256, 0, stream>>>(x, XSPH, XSPL, XB);

    // ---- KNN + k-predictor ----
    gram_mfma<<<dim3(2, 2, 128), 256, 0, stream>>>(XSPH, XSPL, D);
    topk_kernel<<<(128 * NPT) / 4, 256, 0, stream>>>(D, qs, nbr);
    kint2_kernel<<<ROWS / 16, 256, 0, stream>>>(x, KW1, kb1, KW2, kb2, kint, degf);

    // ---- EdgeConv stage 1 ----
    mfma_gemm<4, 0><<<dim3(4, 98), 256, 0, stream>>>(
        XB, nullptr, W1catT, nullptr, nullptr, P1buf, 256, 512,
        nullptr, nullptr, nullptr);
    combine_kernel<1, 1><<<2 * ROWS / 4, 256, 0, stream>>>(
        P1buf, nbr, kint, degf, fc1_b, H1);

    // ---- EdgeConv stage 2 ----
    mfma_gemm<4, 0><<<dim3(4, 196), 256, 0, stream>>>(
        H1, nullptr, W2catT, nullptr, nullptr, P2buf, 256, 512,
        nullptr, nullptr, nullptr);
    combine_kernel<2, 0><<<2 * ROWS / 4, 256, 0, stream>>>(
        P2buf, nbr, kint, degf, fc2_b, H2);

    // ---- fce (bf16 out + fused attention-score partials) ----
    mfma_gemm<20, 0><<<dim3(4, 196), 256, 0, stream>>>(
        H2, nullptr, fcet, fce_b, nullptr, AGGb, 256, 512,
        attn_w, scp, nullptr);

    // ---- softmax (parallel, deterministic) ----
    softmax_part<<<49, 256, 0, stream>>>(scp, attn_b, scores, mpart, spart);
    softmax_fin<<<1, 256, 0, stream>>>(mpart, spart, scores, wgt);

    // ---- final upd GEMM: inline wgt-mix A-staging, composed inout, transposed out ----
    mfma_gemm<9, 2><<<dim3(4, 98), 256, 0, stream>>>(
        XB, XAGGb, updC, bcomp, out, nullptr, 768, 512,
        nullptr, nullptr, wgt);
}

// Round 8
// 242.806 us; speedup vs baseline: 1.1454x; 1.0681x over previous
//
#include <hip/hip_runtime.h>
#include <cstddef>
#include <cstdint>

constexpr int BATCH = 64;
constexpr int CH    = 256;
constexpr int NPT   = 196;
constexpr int ROWS  = BATCH * NPT;   // 12544
constexpr int BSTRIDE = CH * NPT;    // 50176
constexpr int KNB   = 8;             // position 8 (9th) is never valid: k_int <= 8

typedef __bf16 bf16x8 __attribute__((ext_vector_type(8)));
typedef __bf16 bf16x4 __attribute__((ext_vector_type(4)));
typedef _Float16 f16x8 __attribute__((ext_vector_type(8)));
typedef float  f32x4  __attribute__((ext_vector_type(4)));
typedef unsigned long long u64;

__device__ __forceinline__ int src_batch(int b) {
    return (b & ~15) | ((b + 1) & 15);
}

__device__ __forceinline__ void gload_lds16(const void* g, void* l) {
    __builtin_amdgcn_global_load_lds(
        (const __attribute__((address_space(1))) void*)g,
        (__attribute__((address_space(3))) void*)l, 16, 0, 0);
}

// bijective XCD swizzle (m204): nwg must be %8==0
__device__ __forceinline__ int xcd_swz(int lin, int nwg) {
    int q = nwg >> 3;
    return (lin & 7) * q + (lin >> 3);
}

// ------- front mega-kernel: trans_split (0..1023) | qs (1024..1087) | kint2 (1088..1871) -------
__global__ __launch_bounds__(256) void front_kernel(const float* __restrict__ x,
        _Float16* __restrict__ XH, _Float16* __restrict__ XL,
        __bf16* __restrict__ XB, float* __restrict__ qs,
        const float* __restrict__ W1, const float* __restrict__ b1,
        const float* __restrict__ W2, const float* __restrict__ b2,
        int* __restrict__ kint, float* __restrict__ degf) {
    __shared__ __attribute__((aligned(16))) char smem[21056];
    int bid = blockIdx.x;
    int t = threadIdx.x;
    if (bid < 1024) {
        // ---- trans_split ----
        float (*tile)[65] = (float(*)[65])smem;
        int m0 = (bid & 3) * 64, c0 = ((bid >> 2) & 3) * 64, b = bid >> 4;
        const float* xb = x + (size_t)b * BSTRIDE;
        #pragma unroll
        for (int s = 0; s < 16; ++s) {
            int idx = s * 256 + t;
            int cc = idx >> 6, mm = idx & 63;
            int m = m0 + mm;
            float v = (m < NPT) ? xb[(size_t)(c0 + cc) * NPT + m] : 0.f;
            tile[cc][mm] = v;
            if (m < NPT)
                XB[(size_t)b * BSTRIDE + (size_t)(c0 + cc) * NPT + m] = (__bf16)v;
        }
        __syncthreads();
        #pragma unroll
        for (int s = 0; s < 16; ++s) {
            int idx = s * 256 + t;
            int mm = idx >> 6, cc = idx & 63;
            float v = tile[cc][mm];
            _Float16 h = (_Float16)v;
            size_t off = ((size_t)b * 256 + (m0 + mm)) * 256 + c0 + cc;
            XH[off] = h;
            XL[off] = (_Float16)(v - (float)h);
        }
    } else if (bid < 1088) {
        // ---- qs ----
        int b = bid - 1024;
        int m = t;
        if (m >= NPT) return;
        const float* xb = x + (size_t)b * BSTRIDE;
        float acc = 0.f;
        for (int c = 0; c < CH; ++c) {
            float v = xb[c * NPT + m];
            acc = fmaf(v, v, acc);
        }
        qs[b * NPT + m] = acc;
    } else {
        // ---- collapsed k-predictor ----
        float (*xr)[256] = (float(*)[256])smem;                  // 16384 B
        float (*ebuf)[64] = (float(*)[64])(smem + 16384);        //  4096 B
        float (*lg)[9]   = (float(*)[9])(smem + 20480);          //   576 B
        int r0 = (bid - 1088) * 16;
        const float4* xg = (const float4*)(x + (size_t)r0 * 256);
        float4* xs = (float4*)&xr[0][0];
        #pragma unroll
        for (int s = 0; s < 4; ++s) xs[s * 256 + t] = xg[s * 256 + t];
        __syncthreads();
        int w = t >> 6, l = t & 63;
        {
            float bb = b1[l];
            float a0 = bb, a1 = bb, a2 = bb, a3 = bb;
            const float* x0 = xr[w * 4 + 0];
            const float* x1 = xr[w * 4 + 1];
            const float* x2 = xr[w * 4 + 2];
            const float* x3 = xr[w * 4 + 3];
            for (int c = 0; c < 256; ++c) {
                float wv = W1[c * 64 + l];
                a0 = fmaf(x0[c], wv, a0);
                a1 = fmaf(x1[c], wv, a1);
                a2 = fmaf(x2[c], wv, a2);
                a3 = fmaf(x3[c], wv, a3);
            }
            ebuf[w * 4 + 0][l] = fmaxf(a0, 0.f);
            ebuf[w * 4 + 1][l] = fmaxf(a1, 0.f);
            ebuf[w * 4 + 2][l] = fmaxf(a2, 0.f);
            ebuf[w * 4 + 3][l] = fmaxf(a3, 0.f);
        }
        __syncthreads();
        int rr = t >> 4, cc = t & 15;
        if (cc < 9) {
            float acc = b2[cc];
            for (int j = 0; j < 64; ++j)
                acc = fmaf(ebuf[rr][j], W2[j * 9 + cc], acc);
            lg[rr][cc] = acc;
        }
        __syncthreads();
        if (cc == 0) {
            float best = lg[rr][0];
            int bi = 0;
            #pragma unroll
            for (int j = 1; j < 9; ++j)
                if (lg[rr][j] > best) { best = lg[rr][j]; bi = j; }
            kint[r0 + rr] = bi;
            degf[r0 + rr] = (float)bi;
        }
    }
}

// ------- Gram (f16-split MFMA) with FUSED per-wave top-8 extraction -------
// cand[(job*196+row)*4 + tile][8] = sorted (dist,col) u64 keys of this 64-col tile.
__global__ __launch_bounds__(256) void gram_mfma(const _Float16* __restrict__ XH,
        const _Float16* __restrict__ XL, const float* __restrict__ qs,
        u64* __restrict__ cand) {
    __shared__ __attribute__((aligned(16))) _Float16 Ah[128 * 64];
    __shared__ __attribute__((aligned(16))) _Float16 Al[128 * 64];
    __shared__ __attribute__((aligned(16))) _Float16 Bh[128 * 64];
    __shared__ __attribute__((aligned(16))) _Float16 Bl[128 * 64];
    int lin = blockIdx.x + 2 * blockIdx.y + 4 * blockIdx.z;
    int nid = xcd_swz(lin, 512);
    int bx = nid & 1, by = (nid >> 1) & 1;
    int job = nid >> 2;
    int qb = (job < 64) ? job : job - 64;
    int kb = (job < 64) ? qb : src_batch(qb);
    int t = threadIdx.x, w = t >> 6, l = t & 63;
    int r0 = by * 128, c0 = bx * 128;
    int lr = l & 15, lg = l >> 4;
    int wr = (w >> 1) * 64, wc = (w & 1) * 64;
    const _Float16* qh = XH + (size_t)qb * 65536;
    const _Float16* ql = XL + (size_t)qb * 65536;
    const _Float16* kh = XH + (size_t)kb * 65536;
    const _Float16* kl = XL + (size_t)kb * 65536;
    f32x4 acc[4][4] = {};
    for (int k0 = 0; k0 < 256; k0 += 64) {
        #pragma unroll
        for (int i = 0; i < 4; ++i) {
            int row = (w * 4 + i) * 8 + (l >> 3);
            int c8 = l & 7;
            size_t goA = (size_t)(r0 + row) * 256 + k0 + c8 * 8;
            size_t goB = (size_t)(c0 + row) * 256 + k0 + c8 * 8;
            gload_lds16(qh + goA, Ah + (w * 4 + i) * 512);
            gload_lds16(ql + goA, Al + (w * 4 + i) * 512);
            gload_lds16(kh + goB, Bh + (w * 4 + i) * 512);
            gload_lds16(kl + goB, Bl + (w * 4 + i) * 512);
        }
        asm volatile("s_waitcnt vmcnt(0)" ::: "memory");
        __syncthreads();
        #pragma unroll
        for (int ks = 0; ks < 2; ++ks) {
            f16x8 ah[4], al[4], bh[4], bl[4];
            #pragma unroll
            for (int mi = 0; mi < 4; ++mi) {
                ah[mi] = *(const f16x8*)(Ah + (wr + mi * 16 + lr) * 64 + ks * 32 + lg * 8);
                al[mi] = *(const f16x8*)(Al + (wr + mi * 16 + lr) * 64 + ks * 32 + lg * 8);
            }
            #pragma unroll
            for (int ni = 0; ni < 4; ++ni) {
                bh[ni] = *(const f16x8*)(Bh + (wc + ni * 16 + lr) * 64 + ks * 32 + lg * 8);
                bl[ni] = *(const f16x8*)(Bl + (wc + ni * 16 + lr) * 64 + ks * 32 + lg * 8);
            }
            #pragma unroll
            for (int mi = 0; mi < 4; ++mi)
                #pragma unroll
                for (int ni = 0; ni < 4; ++ni) {
                    acc[mi][ni] = __builtin_amdgcn_mfma_f32_16x16x32_f16(
                        ah[mi], bh[ni], acc[mi][ni], 0, 0, 0);
                    acc[mi][ni] = __builtin_amdgcn_mfma_f32_16x16x32_f16(
                        ah[mi], bl[ni], acc[mi][ni], 0, 0, 0);
                    acc[mi][ni] = __builtin_amdgcn_mfma_f32_16x16x32_f16(
                        al[mi], bh[ni], acc[mi][ni], 0, 0, 0);
                }
        }
        __syncthreads();
    }
    // fused top-8 per row over this wave's 64-col tile (uniform control flow;
    // invalid rows do the work but skip the store; shfl groups are 16-lane)
    const float* qsq = qs + qb * NPT;
    const float* qsk = qs + kb * NPT;
    int tile = (c0 + wc) >> 6;
    float ksv[4];
    #pragma unroll
    for (int ni = 0; ni < 4; ++ni) {
        int col = c0 + wc + ni * 16 + lr;
        ksv[ni] = (col < NPT) ? qsk[col] : 0.f;
    }
    #pragma unroll
    for (int mi = 0; mi < 4; ++mi) {
        #pragma unroll
        for (int r = 0; r < 4; ++r) {
            int row = r0 + wr + mi * 16 + lg * 4 + r;
            bool rowvalid = row < NPT;
            float qq = rowvalid ? qsq[row] : 0.f;
            u64 key[4];
            #pragma unroll
            for (int ni = 0; ni < 4; ++ni) {
                int col = c0 + wc + ni * 16 + lr;
                float dist = qq - 2.f * acc[mi][ni][r] + ksv[ni];
                unsigned u = __float_as_uint(dist);
                u = (u & 0x80000000u) ? ~u : (u | 0x80000000u);
                key[ni] = (col < NPT) ? (((u64)u << 32) | (unsigned)col) : ~0ull;
            }
            u64 outk[8];
            #pragma unroll
            for (int it = 0; it < 8; ++it) {
                u64 best = key[0];
                #pragma unroll
                for (int ni = 1; ni < 4; ++ni)
                    best = (key[ni] < best) ? key[ni] : best;
                #pragma unroll
                for (int m = 1; m <= 8; m <<= 1) {
                    u64 o = __shfl_xor(best, m, 64);
                    if (o < best) best = o;
                }
                outk[it] = best;
                #pragma unroll
                for (int ni = 0; ni < 4; ++ni)
                    if (key[ni] == best) key[ni] = ~0ull;
            }
            if (rowvalid && lr == 0) {
                u64* cp = cand + (((size_t)job * NPT + row) * 4 + tile) * 8;
                #pragma unroll
                for (int it = 0; it < 8; ++it) cp[it] = outk[it];
            }
        }
    }
}

// ------- merge 4 sorted per-tile top-8 lists -> global top-8 indices -------
__global__ __launch_bounds__(256) void topk_merge(const u64* __restrict__ cand,
                                                  int* __restrict__ nbr) {
    int rowid = blockIdx.x * 256 + threadIdx.x;   // 98*256 = 25088 exactly
    const u64* c = cand + (size_t)rowid * 32;
    int p0 = 0, p1 = 0, p2 = 0, p3 = 0;
    #pragma unroll
    for (int it = 0; it < 8; ++it) {
        u64 v0 = c[p0], v1 = c[8 + p1], v2 = c[16 + p2], v3 = c[24 + p3];
        u64 best = v0; int bj = 0;
        if (v1 < best) { best = v1; bj = 1; }
        if (v2 < best) { best = v2; bj = 2; }
        if (v3 < best) { best = v3; bj = 3; }
        if (bj == 0) p0 = (p0 < 7) ? p0 + 1 : 7;
        else if (bj == 1) p1 = (p1 < 7) ? p1 + 1 : 7;
        else if (bj == 2) p2 = (p2 < 7) ? p2 + 1 : 7;
        else p3 = (p3 < 7) ? p3 + 1 : 7;
        // sentinel-safe: invalid entries are ~0ull and never win before 8 valid keys
        nbr[(size_t)rowid * KNB + it] = (int)(best & 0xffffffffu);
    }
}

// ------- prep mega-kernel: weight transposes (0..159) | f64 compositions (160..741) -------
__global__ __launch_bounds__(256) void prep_weights(
        const float* __restrict__ fc1_w, const float* __restrict__ fc2_w,
        const float* __restrict__ fce_w, const float* __restrict__ upd_w,
        const float* __restrict__ kp_w, const float* __restrict__ kp_b,
        const float* __restrict__ enc_w, const float* __restrict__ enc_b,
        const float* __restrict__ mu_w, const float* __restrict__ mu_b,
        const float* __restrict__ dec_w, const float* __restrict__ dec_b,
        const float* __restrict__ inout_w, const float* __restrict__ inout_b,
        const float* __restrict__ upd_b,
        __bf16* __restrict__ W1catT, __bf16* __restrict__ W2catT,
        __bf16* __restrict__ fcet, __bf16* __restrict__ updC,
        float* __restrict__ KW1, float* __restrict__ kb1,
        float* __restrict__ KW2, float* __restrict__ kb2,
        float* __restrict__ bcomp) {
    __shared__ float tile[64][65];
    int bid = blockIdx.x;
    int t = threadIdx.x;
    if (bid < 64) {
        const float* W = (bid < 32) ? fc1_w : fc2_w;
        __bf16* WT = (bid < 32) ? W1catT : W2catT;
        int local = bid & 31;
        int n0 = (local >> 2) * 64, k0 = (local & 3) * 64;
        #pragma unroll
        for (int s = 0; s < 16; ++s) {
            int idx = s * 256 + t;
            int kk = idx >> 6, nn = idx & 63;
            float v;
            if (n0 < 256)
                v = W[(size_t)(k0 + kk) * 256 + n0 + nn] -
                    W[(size_t)(k0 + kk + 256) * 256 + n0 + nn];
            else
                v = W[(size_t)(k0 + kk + 256) * 256 + (n0 - 256) + nn];
            tile[kk][nn] = v;
        }
        __syncthreads();
        #pragma unroll
        for (int s = 0; s < 16; ++s) {
            int idx = s * 256 + t;
            int nn = idx >> 6, kk = idx & 63;
            WT[(size_t)(n0 + nn) * 256 + k0 + kk] = (__bf16)tile[kk][nn];
        }
    } else if (bid < 96) {
        int local = bid - 64;
        int n0 = (local >> 2) * 64, k0 = (local & 3) * 64;
        #pragma unroll
        for (int s = 0; s < 16; ++s) {
            int idx = s * 256 + t;
            int kk = idx >> 6, nn = idx & 63;
            tile[kk][nn] = fce_w[(size_t)(k0 + kk) * 512 + n0 + nn];
        }
        __syncthreads();
        #pragma unroll
        for (int s = 0; s < 16; ++s) {
            int idx = s * 256 + t;
            int nn = idx >> 6, kk = idx & 63;
            fcet[(size_t)(n0 + nn) * 256 + k0 + kk] = (__bf16)tile[kk][nn];
        }
    } else if (bid < 160) {
        int local = bid - 96;                       // 0..63
        int k0 = (local >> 3) * 64, n0 = (local & 7) * 64;
        #pragma unroll
        for (int s = 0; s < 16; ++s) {
            int idx = s * 256 + t;
            int kk = idx >> 6, nn = idx & 63;
            tile[kk][nn] = upd_w[(size_t)(512 + k0 + kk) * 512 + n0 + nn];
        }
        __syncthreads();
        #pragma unroll
        for (int s = 0; s < 16; ++s) {
            int idx = s * 256 + t;
            int nn = idx >> 6, kk = idx & 63;
            updC[(size_t)(n0 + nn) * 768 + 256 + k0 + kk] = (__bf16)tile[kk][nn];
        }
    } else if (bid < 224) {
        int i = (bid - 160) * 4 + (t >> 6);
        int j = t & 63;
        double acc = 0.0;
        for (int k = 0; k < 500; ++k)
            acc += (double)kp_w[(size_t)i * 500 + k] * (double)enc_w[(size_t)k * 64 + j];
        KW1[i * 64 + j] = (float)acc;
    } else if (bid == 224) {
        int j = t;
        if (j < 64) {
            double acc = (double)enc_b[j];
            for (int k = 0; k < 500; ++k)
                acc += (double)kp_b[k] * (double)enc_w[(size_t)k * 64 + j];
            kb1[j] = (float)acc;
        }
    } else if (bid < 228) {
        int e = (bid - 225) * 256 + t;
        if (e < 576) {
            int i = e / 9, j = e - (e / 9) * 9;
            double acc = 0.0;
            for (int k = 0; k < 32; ++k)
                acc += (double)mu_w[(size_t)i * 32 + k] * (double)dec_w[(size_t)k * 9 + j];
            KW2[e] = (float)acc;
        } else if (e < 585) {
            int j = e - 576;
            double acc = (double)dec_b[j];
            for (int k = 0; k < 32; ++k)
                acc += (double)mu_b[k] * (double)dec_w[(size_t)k * 9 + j];
            kb2[j] = (float)acc;
        }
    } else if (bid < 740) {
        int e = (bid - 228) * 256 + t;              // 0..131071
        int k = e >> 9, n = e & 511;
        double acc = 0.0;
        for (int j = 0; j < 512; ++j)
            acc += (double)inout_w[(size_t)k * 512 + j] * (double)upd_w[(size_t)j * 512 + n];
        updC[(size_t)n * 768 + k] = (__bf16)(float)acc;
    } else {
        int n = (bid - 740) * 256 + t;              // 0..511
        double acc = (double)upd_b[n];
        for (int j = 0; j < 512; ++j)
            acc += (double)inout_b[j] * (double)upd_w[(size_t)j * 512 + n];
        bcomp[n] = (float)acc;
    }
}

// ------- combine: H[r] = (relu?)( deg*(Pa[self]+bias) + sum_nbr Pb ), XCD-swizzled -------
template<int STAGE, int RELU>
__global__ __launch_bounds__(256) void combine_kernel(const __bf16* __restrict__ P,
        const int* __restrict__ nbr, const int* __restrict__ kint_,
        const float* __restrict__ degf, const float* __restrict__ bias,
        __bf16* __restrict__ H) {
    int g = threadIdx.x >> 6, lane = threadIdx.x & 63;
    int nid = xcd_swz(blockIdx.x, 2 * ROWS / 4);
    int r = nid * 4 + g;                        // 0..2*ROWS
    int branch = (r >= ROWS);
    int rr = r - branch * ROWS;
    int b = rr / NPT, i = rr - b * NPT;
    size_t srow, mbase;
    if constexpr (STAGE == 1) {
        int fb = branch ? src_batch(b) : b;
        srow = (size_t)fb * NPT + i;
        mbase = (size_t)fb * NPT;
    } else {
        srow = (size_t)r;
        mbase = (size_t)branch * ROWS + (size_t)b * NPT;
    }
    const int* nb = nbr + (size_t)branch * ((size_t)ROWS * KNB) + (size_t)rr * KNB;
    bf16x4 sv = *(const bf16x4*)(P + srow * 512 + lane * 4);
    float4 bv = *(const float4*)(bias + lane * 4);
    float s0 = 0.f, s1 = 0.f, s2 = 0.f, s3 = 0.f;
    int kk = kint_[rr];
    for (int tt = 0; tt < kk; ++tt) {
        int m = nb[tt];
        bf16x4 v = *(const bf16x4*)(P + (mbase + m) * 512 + 256 + lane * 4);
        s0 += (float)v[0]; s1 += (float)v[1]; s2 += (float)v[2]; s3 += (float)v[3];
    }
    float dg = degf[rr];
    float o0 = fmaf(dg, (float)sv[0] + bv.x, s0);
    float o1 = fmaf(dg, (float)sv[1] + bv.y, s1);
    float o2 = fmaf(dg, (float)sv[2] + bv.z, s2);
    float o3 = fmaf(dg, (float)sv[3] + bv.w, s3);
    if constexpr (RELU) {
        o0 = fmaxf(o0, 0.f); o1 = fmaxf(o1, 0.f);
        o2 = fmaxf(o2, 0.f); o3 = fmaxf(o3, 0.f);
    }
    bf16x4 ov;
    ov[0] = (__bf16)o0; ov[1] = (__bf16)o1; ov[2] = (__bf16)o2; ov[3] = (__bf16)o3;
    *(bf16x4*)(H + (size_t)r * 256 + lane * 4) = ov;
}

// ---------------- bf16 MFMA GEMM (XCD-swizzled) ----------------
// FLAGS: 1=RELU, 4=bf16 out, 8=transposed out[b][c][i], 16=scores epilogue (implies bf16 out).
// CONCAT: 0 plain; 2 = A row = [A0(256) | wgt-mix of A1/A1+ROWS*512 (512)], K=768.
template<int FLAGS, int CONCAT>
__global__ __launch_bounds__(256) void mfma_gemm(
    const __bf16* __restrict__ A0, const __bf16* __restrict__ A1,
    const __bf16* __restrict__ WT, const float* __restrict__ bias,
    float* __restrict__ Cf, __bf16* __restrict__ Cb, int K, int N,
    const float* __restrict__ aw, float* __restrict__ scp,
    const float* __restrict__ wgt) {
    constexpr int SMEMB = (FLAGS & 8) ? (128 * 129 * 4) : (2 * 128 * 64 * 2);
    __shared__ __attribute__((aligned(16))) char smem[SMEMB];
    __bf16* As = (__bf16*)smem;
    __bf16* Bs = As + 128 * 64;
    int lin = blockIdx.x + 4 * blockIdx.y;
    int nid = xcd_swz(lin, 4 * gridDim.y);
    int bx = nid & 3, by = nid >> 2;
    int t = threadIdx.x, w = t >> 6, l = t & 63;
    int r0 = by * 128, c0 = bx * 128;
    int lr = l & 15, lg = l >> 4;
    int wr = (w >> 1) * 64, wc = (w & 1) * 64;
    f32x4 acc[4][4] = {};
    for (int k0 = 0; k0 < K; k0 += 64) {
        #pragma unroll
        for (int i = 0; i < 4; ++i) {
            int row = (w * 4 + i) * 8 + (l >> 3);
            int c8 = l & 7;
            if constexpr (CONCAT == 2) {
                if (k0 < 256) {
                    gload_lds16(A0 + (size_t)(r0 + row) * 256 + k0 + c8 * 8,
                                As + (w * 4 + i) * 512);
                } else {
                    int kk2 = k0 - 256 + c8 * 8;
                    size_t gr = (size_t)(r0 + row);
                    bf16x8 xa = *(const bf16x8*)(A1 + gr * 512 + kk2);
                    bf16x8 ya = *(const bf16x8*)(A1 + ((size_t)ROWS + gr) * 512 + kk2);
                    float wv = wgt[gr];
                    bf16x8 mx;
                    #pragma unroll
                    for (int j = 0; j < 8; ++j)
                        mx[j] = (__bf16)(wv * (float)xa[j] + (1.f - wv) * (float)ya[j]);
                    *(bf16x8*)(As + (w * 4 + i) * 512 + l * 8) = mx;
                }
            } else {
                gload_lds16(A0 + (size_t)(r0 + row) * K + k0 + c8 * 8,
                            As + (w * 4 + i) * 512);
            }
            gload_lds16(WT + (size_t)(c0 + row) * K + k0 + c8 * 8,
                        Bs + (w * 4 + i) * 512);
        }
        asm volatile("s_waitcnt vmcnt(0)" ::: "memory");
        __syncthreads();
        #pragma unroll
        for (int ks = 0; ks < 2; ++ks) {
            bf16x8 af[4], bfr[4];
            #pragma unroll
            for (int mi = 0; mi < 4; ++mi)
                af[mi] = *(const bf16x8*)(As + (wr + mi * 16 + lr) * 64 + ks * 32 + lg * 8);
            #pragma unroll
            for (int ni = 0; ni < 4; ++ni)
                bfr[ni] = *(const bf16x8*)(Bs + (wc + ni * 16 + lr) * 64 + ks * 32 + lg * 8);
            #pragma unroll
            for (int mi = 0; mi < 4; ++mi)
                #pragma unroll
                for (int ni = 0; ni < 4; ++ni)
                    acc[mi][ni] = __builtin_amdgcn_mfma_f32_16x16x32_bf16(
                        af[mi], bfr[ni], acc[mi][ni], 0, 0, 0);
        }
        __syncthreads();
    }
    if constexpr ((FLAGS & 8) != 0) {
        float* tile = (float*)smem;
        #pragma unroll
        for (int mi = 0; mi < 4; ++mi)
            #pragma unroll
            for (int r = 0; r < 4; ++r) {
                int rrow = wr + mi * 16 + lg * 4 + r;
                #pragma unroll
                for (int ni = 0; ni < 4; ++ni) {
                    int ccol = wc + ni * 16 + lr;
                    float v = acc[mi][ni][r];
                    if (bias) v += bias[c0 + ccol];
                    if constexpr ((FLAGS & 1) != 0) v = fmaxf(v, 0.f);
                    tile[rrow * 129 + ccol] = v;
                }
            }
        __syncthreads();
        int cc = t >> 6, rr2 = t & 63;
        #pragma unroll
        for (int cs = 0; cs < 128; cs += 4) {
            #pragma unroll
            for (int h = 0; h < 2; ++h) {
                int row = r0 + rr2 + h * 64;
                int bb = row / NPT, ii = row - bb * NPT;
                Cf[((size_t)bb * 512 + (c0 + cc + cs)) * NPT + ii] =
                    tile[(rr2 + h * 64) * 129 + cc + cs];
            }
        }
    } else if constexpr ((FLAGS & 16) != 0) {
        int half = (r0 >= ROWS) ? 1 : 0;
        float ps[4][4] = {};
        #pragma unroll
        for (int mi = 0; mi < 4; ++mi)
            #pragma unroll
            for (int r = 0; r < 4; ++r) {
                int row = r0 + wr + mi * 16 + lg * 4 + r;
                #pragma unroll
                for (int ni = 0; ni < 4; ++ni) {
                    int col = c0 + wc + ni * 16 + lr;
                    float v = acc[mi][ni][r] + bias[col];
                    Cb[(size_t)row * N + col] = (__bf16)v;
                    ps[mi][r] = fmaf(v, aw[half * 512 + col], ps[mi][r]);
                }
            }
        #pragma unroll
        for (int m = 1; m <= 8; m <<= 1)
            #pragma unroll
            for (int mi = 0; mi < 4; ++mi)
                #pragma unroll
                for (int r = 0; r < 4; ++r)
                    ps[mi][r] += __shfl_xor(ps[mi][r], m, 64);
        if (lr == 0) {
            int slot = half * 8 + bx * 2 + (w & 1);
            #pragma unroll
            for (int mi = 0; mi < 4; ++mi)
                #pragma unroll
                for (int r = 0; r < 4; ++r) {
                    int sr = r0 - half * ROWS + wr + mi * 16 + lg * 4 + r;
                    scp[(size_t)slot * ROWS + sr] = ps[mi][r];
                }
        }
    } else {
        #pragma unroll
        for (int mi = 0; mi < 4; ++mi) {
            #pragma unroll
            for (int r = 0; r < 4; ++r) {
                int row = r0 + wr + mi * 16 + lg * 4 + r;
                #pragma unroll
                for (int ni = 0; ni < 4; ++ni) {
                    int col = c0 + wc + ni * 16 + lr;
                    float v = acc[mi][ni][r];
                    if (bias) v += bias[col];
                    if constexpr ((FLAGS & 1) != 0) v = fmaxf(v, 0.f);
                    if constexpr ((FLAGS & 4) != 0)
                        Cb[(size_t)row * N + col] = (__bf16)v;
                    else
                        Cf[(size_t)row * N + col] = v;
                }
            }
        }
    }
}

// ------- softmax stage 1 -------
__global__ __launch_bounds__(256) void softmax_part(const float* __restrict__ scp,
        const float* __restrict__ ab, float* __restrict__ scores,
        float* __restrict__ mpart, float* __restrict__ spart) {
    __shared__ float red[256];
    int t = threadIdx.x;
    int sr = blockIdx.x * 256 + t;              // 49*256 = ROWS exactly
    float s = ab[0];
    #pragma unroll
    for (int i = 0; i < 16; ++i) s += scp[(size_t)i * ROWS + sr];
    scores[sr] = s;
    red[t] = s; __syncthreads();
    for (int off = 128; off; off >>= 1) {
        if (t < off) red[t] = fmaxf(red[t], red[t + off]);
        __syncthreads();
    }
    float mb = red[0]; __syncthreads();
    red[t] = expf(s - mb); __syncthreads();
    for (int off = 128; off; off >>= 1) {
        if (t < off) red[t] += red[t + off];
        __syncthreads();
    }
    if (t == 0) { mpart[blockIdx.x] = mb; spart[blockIdx.x] = red[0]; }
}

// ------- softmax stage 2 -------
__global__ __launch_bounds__(256) void softmax_fin(const float* __restrict__ mpart,
        const float* __restrict__ spart, const float* __restrict__ scores,
        float* __restrict__ wgt) {
    __shared__ float MS[2];
    if (threadIdx.x == 0) {
        float M = mpart[0];
        for (int i = 1; i < 49; ++i) M = fmaxf(M, mpart[i]);
        float S = 0.f;
        for (int i = 0; i < 49; ++i) S += spart[i] * expf(mpart[i] - M);
        MS[0] = M; MS[1] = S;
    }
    __syncthreads();
    float M = MS[0], denom = MS[1];
    for (int i = threadIdx.x; i < ROWS; i += 256)
        wgt[i] = expf(scores[i] - M) / denom;
}

extern "C" void kernel_launch(void* const* d_in, const int* in_sizes, int n_in,
                              void* d_out, int out_size, void* d_ws, size_t ws_size,
                              hipStream_t stream) {
    (void)in_sizes; (void)n_in; (void)out_size; (void)ws_size;
    const float* x       = (const float*)d_in[0];
    const float* fc1_w   = (const float*)d_in[1];
    const float* fc1_b   = (const float*)d_in[2];
    const float* fc2_w   = (const float*)d_in[3];
    const float* fc2_b   = (const float*)d_in[4];
    const float* fce_w   = (const float*)d_in[5];
    const float* fce_b   = (const float*)d_in[6];
    const float* inout_w = (const float*)d_in[7];
    const float* inout_b = (const float*)d_in[8];
    const float* attn_w  = (const float*)d_in[9];
    const float* attn_b  = (const float*)d_in[10];
    const float* upd_w   = (const float*)d_in[11];
    const float* upd_b   = (const float*)d_in[12];
    const float* kp_w    = (const float*)d_in[13];
    const float* kp_b    = (const float*)d_in[14];
    const float* enc_w   = (const float*)d_in[15];
    const float* enc_b   = (const float*)d_in[16];
    const float* mu_w    = (const float*)d_in[17];
    const float* mu_b    = (const float*)d_in[18];
    const float* dec_w   = (const float*)d_in[19];
    const float* dec_b   = (const float*)d_in[20];
    float* out = (float*)d_out;

    char* base = (char*)d_ws;
    size_t o = 0;
    auto alloc = [&](size_t bytes) -> void* {
        void* p = base + o;
        o += (bytes + 255) & ~(size_t)255;
        return p;
    };
    float* qs     = (float*)alloc(ROWS * 4);
    float* degf   = (float*)alloc(ROWS * 4);
    float* scores = (float*)alloc(ROWS * 4);
    float* wgt    = (float*)alloc(ROWS * 4);
    int*   kint   = (int*)  alloc(ROWS * 4);
    float* KW1    = (float*)alloc(256 * 64 * 4);
    float* kb1    = (float*)alloc(64 * 4);
    float* KW2    = (float*)alloc(64 * 9 * 4);
    float* kb2    = (float*)alloc(9 * 4);
    float* bcomp  = (float*)alloc(512 * 4);
    float* scp    = (float*)alloc((size_t)16 * ROWS * 4);           //  0.80 MB
    float* mpart  = (float*)alloc(64 * 4);
    float* spart  = (float*)alloc(64 * 4);
    int*   nbr    = (int*)  alloc((size_t)128 * NPT * KNB * 4);     //  0.80 MB
    u64*   cand   = (u64*)  alloc((size_t)128 * NPT * 4 * 8 * 8);   //  6.42 MB
    char*  regD   = (char*) alloc((size_t)ROWS * 512 * 2);          // 12.85 MB
    __bf16* XB    = (__bf16*)alloc((size_t)ROWS * 256 * 2);         //  6.42 MB
    __bf16* H1    = (__bf16*)alloc((size_t)2 * ROWS * 256 * 2);     // 12.85 MB
    __bf16* H2    = (__bf16*)alloc((size_t)2 * ROWS * 256 * 2);     // 12.85 MB
    char*  regAGG = (char*) alloc((size_t)2 * ROWS * 512 * 4);      // 51.38 MB
    __bf16* W1catT= (__bf16*)alloc((size_t)512 * 256 * 2);
    __bf16* W2catT= (__bf16*)alloc((size_t)512 * 256 * 2);
    __bf16* fcet  = (__bf16*)alloc((size_t)512 * 256 * 2);
    __bf16* updC  = (__bf16*)alloc((size_t)512 * 768 * 2);
    // --- aliases (stream-order safe) ---
    __bf16* P1buf = (__bf16*)regD;                 // stage-1 P, dead after combine1
    _Float16* XSPH = (_Float16*)regAGG;            // dead after gram
    _Float16* XSPL = XSPH + (size_t)64 * 256 * 256;
    __bf16* P2buf = (__bf16*)regAGG;               // stage-2 P, dead after combine2
    __bf16* AGGb  = (__bf16*)regAGG;               // fce output (bf16), 25.7 MB
    __bf16* XAGGb = AGGb;

    // ---- prep (weights + composed k-predictor) ----
    prep_weights<<<742, 256, 0, stream>>>(fc1_w, fc2_w, fce_w, upd_w,
                                          kp_w, kp_b, enc_w, enc_b,
                                          mu_w, mu_b, dec_w, dec_b,
                                          inout_w, inout_b, upd_b,
                                          W1catT, W2catT, fcet, updC,
                                          KW1, kb1, KW2, kb2, bcomp);
    // ---- front (trans_split + qs + collapsed k-predictor) ----
    front_kernel<<<1872, 256, 0, stream>>>(x, XSPH, XSPL, XB, qs,
                                           KW1, kb1, KW2, kb2, kint, degf);

    // ---- KNN: gram with fused per-tile top-8, then 4-way merge ----
    gram_mfma<<<dim3(2, 2, 128), 256, 0, stream>>>(XSPH, XSPL, qs, cand);
    topk_merge<<<98, 256, 0, stream>>>(cand, nbr);

    // ---- EdgeConv stage 1 ----
    mfma_gemm<4, 0><<<dim3(4, 98), 256, 0, stream>>>(
        XB, nullptr, W1catT, nullptr, nullptr, P1buf, 256, 512,
        nullptr, nullptr, nullptr);
    combine_kernel<1, 1><<<2 * ROWS / 4, 256, 0, stream>>>(
        P1buf, nbr, kint, degf, fc1_b, H1);

    // ---- EdgeConv stage 2 ----
    mfma_gemm<4, 0><<<dim3(4, 196), 256, 0, stream>>>(
        H1, nullptr, W2catT, nullptr, nullptr, P2buf, 256, 512,
        nullptr, nullptr, nullptr);
    combine_kernel<2, 0><<<2 * ROWS / 4, 256, 0, stream>>>(
        P2buf, nbr, kint, degf, fc2_b, H2);

    // ---- fce (bf16 out + fused attention-score partials) ----
    mfma_gemm<20, 0><<<dim3(4, 196), 256, 0, stream>>>(
        H2, nullptr, fcet, fce_b, nullptr, AGGb, 256, 512,
        attn_w, scp, nullptr);

    // ---- softmax (parallel, deterministic) ----
    softmax_part<<<49, 256, 0, stream>>>(scp, attn_b, scores, mpart, spart);
    softmax_fin<<<1, 256, 0, stream>>>(mpart, spart, scores, wgt);

    // ---- final upd GEMM: inline wgt-mix A-staging, composed inout, transposed out ----
    mfma_gemm<9, 2><<<dim3(4, 98), 256, 0, stream>>>(
        XB, XAGGb, updC, bcomp, out, nullptr, 768, 512,
        nullptr, nullptr, wgt);
}

// Round 9
// 230.974 us; speedup vs baseline: 1.2041x; 1.0512x over previous
//
#include <hip/hip_runtime.h>
#include <cstddef>
#include <cstdint>

constexpr int BATCH = 64;
constexpr int CH    = 256;
constexpr int NPT   = 196;
constexpr int ROWS  = BATCH * NPT;   // 12544
constexpr int BSTRIDE = CH * NPT;    // 50176
constexpr int KNB   = 8;             // position 8 (9th) is never valid: k_int <= 8

typedef __bf16 bf16x8 __attribute__((ext_vector_type(8)));
typedef __bf16 bf16x4 __attribute__((ext_vector_type(4)));
typedef _Float16 f16x8 __attribute__((ext_vector_type(8)));
typedef float  f32x4  __attribute__((ext_vector_type(4)));
typedef unsigned long long u64;

__device__ __forceinline__ int src_batch(int b) {
    return (b & ~15) | ((b + 1) & 15);
}

__device__ __forceinline__ void gload_lds16(const void* g, void* l) {
    __builtin_amdgcn_global_load_lds(
        (const __attribute__((address_space(1))) void*)g,
        (__attribute__((address_space(3))) void*)l, 16, 0, 0);
}

// bijective XCD swizzle (m204): nwg must be %8==0
__device__ __forceinline__ int xcd_swz(int lin, int nwg) {
    int q = nwg >> 3;
    return (lin & 7) * q + (lin >> 3);
}

// DPP row_ror (16-lane row rotate) on u64 — VALU-pipe, replaces ds_swizzle shfl.
// ctrl: row_ror:r = 0x120 | r
template<int CTRL>
__device__ __forceinline__ u64 dpp_ror_u64(u64 v) {
    int lo = __builtin_amdgcn_update_dpp(0, (int)(unsigned)(v & 0xffffffffu),
                                         CTRL, 0xf, 0xf, true);
    int hi = __builtin_amdgcn_update_dpp(0, (int)(unsigned)(v >> 32),
                                         CTRL, 0xf, 0xf, true);
    return ((u64)(unsigned)hi << 32) | (unsigned)lo;
}

// ------- front mega-kernel: trans_split (0..1023) | qs (1024..1087) | kint2 (1088..1871) -------
__global__ __launch_bounds__(256) void front_kernel(const float* __restrict__ x,
        _Float16* __restrict__ XH, _Float16* __restrict__ XL,
        __bf16* __restrict__ XB, float* __restrict__ qs,
        const float* __restrict__ W1, const float* __restrict__ b1,
        const float* __restrict__ W2, const float* __restrict__ b2,
        int* __restrict__ kint, float* __restrict__ degf) {
    __shared__ __attribute__((aligned(16))) char smem[21056];
    int bid = blockIdx.x;
    int t = threadIdx.x;
    if (bid < 1024) {
        // ---- trans_split ----
        float (*tile)[65] = (float(*)[65])smem;
        int m0 = (bid & 3) * 64, c0 = ((bid >> 2) & 3) * 64, b = bid >> 4;
        const float* xb = x + (size_t)b * BSTRIDE;
        #pragma unroll
        for (int s = 0; s < 16; ++s) {
            int idx = s * 256 + t;
            int cc = idx >> 6, mm = idx & 63;
            int m = m0 + mm;
            float v = (m < NPT) ? xb[(size_t)(c0 + cc) * NPT + m] : 0.f;
            tile[cc][mm] = v;
            if (m < NPT)
                XB[(size_t)b * BSTRIDE + (size_t)(c0 + cc) * NPT + m] = (__bf16)v;
        }
        __syncthreads();
        #pragma unroll
        for (int s = 0; s < 16; ++s) {
            int idx = s * 256 + t;
            int mm = idx >> 6, cc = idx & 63;
            float v = tile[cc][mm];
            _Float16 h = (_Float16)v;
            size_t off = ((size_t)b * 256 + (m0 + mm)) * 256 + c0 + cc;
            XH[off] = h;
            XL[off] = (_Float16)(v - (float)h);
        }
    } else if (bid < 1088) {
        // ---- qs ----
        int b = bid - 1024;
        int m = t;
        if (m >= NPT) return;
        const float* xb = x + (size_t)b * BSTRIDE;
        float acc = 0.f;
        for (int c = 0; c < CH; ++c) {
            float v = xb[c * NPT + m];
            acc = fmaf(v, v, acc);
        }
        qs[b * NPT + m] = acc;
    } else {
        // ---- collapsed k-predictor ----
        float (*xr)[256] = (float(*)[256])smem;                  // 16384 B
        float (*ebuf)[64] = (float(*)[64])(smem + 16384);        //  4096 B
        float (*lg)[9]   = (float(*)[9])(smem + 20480);          //   576 B
        int r0 = (bid - 1088) * 16;
        const float4* xg = (const float4*)(x + (size_t)r0 * 256);
        float4* xs = (float4*)&xr[0][0];
        #pragma unroll
        for (int s = 0; s < 4; ++s) xs[s * 256 + t] = xg[s * 256 + t];
        __syncthreads();
        int w = t >> 6, l = t & 63;
        {
            float bb = b1[l];
            float a0 = bb, a1 = bb, a2 = bb, a3 = bb;
            const float* x0 = xr[w * 4 + 0];
            const float* x1 = xr[w * 4 + 1];
            const float* x2 = xr[w * 4 + 2];
            const float* x3 = xr[w * 4 + 3];
            for (int c = 0; c < 256; ++c) {
                float wv = W1[c * 64 + l];
                a0 = fmaf(x0[c], wv, a0);
                a1 = fmaf(x1[c], wv, a1);
                a2 = fmaf(x2[c], wv, a2);
                a3 = fmaf(x3[c], wv, a3);
            }
            ebuf[w * 4 + 0][l] = fmaxf(a0, 0.f);
            ebuf[w * 4 + 1][l] = fmaxf(a1, 0.f);
            ebuf[w * 4 + 2][l] = fmaxf(a2, 0.f);
            ebuf[w * 4 + 3][l] = fmaxf(a3, 0.f);
        }
        __syncthreads();
        int rr = t >> 4, cc = t & 15;
        if (cc < 9) {
            float acc = b2[cc];
            for (int j = 0; j < 64; ++j)
                acc = fmaf(ebuf[rr][j], W2[j * 9 + cc], acc);
            lg[rr][cc] = acc;
        }
        __syncthreads();
        if (cc == 0) {
            float best = lg[rr][0];
            int bi = 0;
            #pragma unroll
            for (int j = 1; j < 9; ++j)
                if (lg[rr][j] > best) { best = lg[rr][j]; bi = j; }
            kint[r0 + rr] = bi;
            degf[r0 + rr] = (float)bi;
        }
    }
}

// ------- Gram (f16-split MFMA) with FUSED per-wave top-8 extraction (DPP reduce) -------
// cand[(job*196+row)*4 + tile][8] = sorted (dist,col) u64 keys of this 64-col tile.
__global__ __launch_bounds__(256) void gram_mfma(const _Float16* __restrict__ XH,
        const _Float16* __restrict__ XL, const float* __restrict__ qs,
        u64* __restrict__ cand) {
    __shared__ __attribute__((aligned(16))) _Float16 Ah[128 * 64];
    __shared__ __attribute__((aligned(16))) _Float16 Al[128 * 64];
    __shared__ __attribute__((aligned(16))) _Float16 Bh[128 * 64];
    __shared__ __attribute__((aligned(16))) _Float16 Bl[128 * 64];
    int lin = blockIdx.x + 2 * blockIdx.y + 4 * blockIdx.z;
    int nid = xcd_swz(lin, 512);
    int bx = nid & 1, by = (nid >> 1) & 1;
    int job = nid >> 2;
    int qb = (job < 64) ? job : job - 64;
    int kb = (job < 64) ? qb : src_batch(qb);
    int t = threadIdx.x, w = t >> 6, l = t & 63;
    int r0 = by * 128, c0 = bx * 128;
    int lr = l & 15, lg = l >> 4;
    int wr = (w >> 1) * 64, wc = (w & 1) * 64;
    const _Float16* qh = XH + (size_t)qb * 65536;
    const _Float16* ql = XL + (size_t)qb * 65536;
    const _Float16* kh = XH + (size_t)kb * 65536;
    const _Float16* kl = XL + (size_t)kb * 65536;
    f32x4 acc[4][4] = {};
    for (int k0 = 0; k0 < 256; k0 += 64) {
        #pragma unroll
        for (int i = 0; i < 4; ++i) {
            int row = (w * 4 + i) * 8 + (l >> 3);
            int c8 = l & 7;
            size_t goA = (size_t)(r0 + row) * 256 + k0 + c8 * 8;
            size_t goB = (size_t)(c0 + row) * 256 + k0 + c8 * 8;
            gload_lds16(qh + goA, Ah + (w * 4 + i) * 512);
            gload_lds16(ql + goA, Al + (w * 4 + i) * 512);
            gload_lds16(kh + goB, Bh + (w * 4 + i) * 512);
            gload_lds16(kl + goB, Bl + (w * 4 + i) * 512);
        }
        asm volatile("s_waitcnt vmcnt(0)" ::: "memory");
        __syncthreads();
        #pragma unroll
        for (int ks = 0; ks < 2; ++ks) {
            f16x8 ah[4], al[4], bh[4], bl[4];
            #pragma unroll
            for (int mi = 0; mi < 4; ++mi) {
                ah[mi] = *(const f16x8*)(Ah + (wr + mi * 16 + lr) * 64 + ks * 32 + lg * 8);
                al[mi] = *(const f16x8*)(Al + (wr + mi * 16 + lr) * 64 + ks * 32 + lg * 8);
            }
            #pragma unroll
            for (int ni = 0; ni < 4; ++ni) {
                bh[ni] = *(const f16x8*)(Bh + (wc + ni * 16 + lr) * 64 + ks * 32 + lg * 8);
                bl[ni] = *(const f16x8*)(Bl + (wc + ni * 16 + lr) * 64 + ks * 32 + lg * 8);
            }
            #pragma unroll
            for (int mi = 0; mi < 4; ++mi)
                #pragma unroll
                for (int ni = 0; ni < 4; ++ni) {
                    acc[mi][ni] = __builtin_amdgcn_mfma_f32_16x16x32_f16(
                        ah[mi], bh[ni], acc[mi][ni], 0, 0, 0);
                    acc[mi][ni] = __builtin_amdgcn_mfma_f32_16x16x32_f16(
                        ah[mi], bl[ni], acc[mi][ni], 0, 0, 0);
                    acc[mi][ni] = __builtin_amdgcn_mfma_f32_16x16x32_f16(
                        al[mi], bh[ni], acc[mi][ni], 0, 0, 0);
                }
        }
        __syncthreads();
    }
    // fused top-8 per row over this wave's 64-col tile.
    // 16-lane reduction via DPP row_ror (VALU pipe) — same key set, same
    // comparator as the shfl version => bit-identical selection.
    const float* qsq = qs + qb * NPT;
    const float* qsk = qs + kb * NPT;
    int tile = (c0 + wc) >> 6;
    float ksv[4];
    #pragma unroll
    for (int ni = 0; ni < 4; ++ni) {
        int col = c0 + wc + ni * 16 + lr;
        ksv[ni] = (col < NPT) ? qsk[col] : 0.f;
    }
    #pragma unroll
    for (int mi = 0; mi < 4; ++mi) {
        #pragma unroll
        for (int r = 0; r < 4; ++r) {
            // wave-uniform skip: smallest row of this (mi,r) slice is r0+wr+mi*16+r
            if (r0 + wr + mi * 16 + r >= NPT) continue;
            int row = r0 + wr + mi * 16 + lg * 4 + r;
            bool rowvalid = row < NPT;
            float qq = rowvalid ? qsq[row] : 0.f;
            u64 key[4];
            #pragma unroll
            for (int ni = 0; ni < 4; ++ni) {
                int col = c0 + wc + ni * 16 + lr;
                float dist = qq - 2.f * acc[mi][ni][r] + ksv[ni];
                unsigned u = __float_as_uint(dist);
                u = (u & 0x80000000u) ? ~u : (u | 0x80000000u);
                key[ni] = (col < NPT) ? (((u64)u << 32) | (unsigned)col) : ~0ull;
            }
            u64 outk[8];
            #pragma unroll
            for (int it = 0; it < 8; ++it) {
                u64 best = key[0];
                #pragma unroll
                for (int ni = 1; ni < 4; ++ni)
                    best = (key[ni] < best) ? key[ni] : best;
                { u64 o = dpp_ror_u64<0x128>(best); if (o < best) best = o; }
                { u64 o = dpp_ror_u64<0x124>(best); if (o < best) best = o; }
                { u64 o = dpp_ror_u64<0x122>(best); if (o < best) best = o; }
                { u64 o = dpp_ror_u64<0x121>(best); if (o < best) best = o; }
                outk[it] = best;
                #pragma unroll
                for (int ni = 0; ni < 4; ++ni)
                    if (key[ni] == best) key[ni] = ~0ull;
            }
            if (rowvalid && lr == 0) {
                u64* cp = cand + (((size_t)job * NPT + row) * 4 + tile) * 8;
                #pragma unroll
                for (int it = 0; it < 8; ++it) cp[it] = outk[it];
            }
        }
    }
}

// ------- merge 4 sorted per-tile top-8 lists -> global top-8 indices -------
__global__ __launch_bounds__(256) void topk_merge(const u64* __restrict__ cand,
                                                  int* __restrict__ nbr) {
    int rowid = blockIdx.x * 256 + threadIdx.x;   // 98*256 = 25088 exactly
    const u64* c = cand + (size_t)rowid * 32;
    int p0 = 0, p1 = 0, p2 = 0, p3 = 0;
    #pragma unroll
    for (int it = 0; it < 8; ++it) {
        u64 v0 = c[p0], v1 = c[8 + p1], v2 = c[16 + p2], v3 = c[24 + p3];
        u64 best = v0; int bj = 0;
        if (v1 < best) { best = v1; bj = 1; }
        if (v2 < best) { best = v2; bj = 2; }
        if (v3 < best) { best = v3; bj = 3; }
        if (bj == 0) p0 = (p0 < 7) ? p0 + 1 : 7;
        else if (bj == 1) p1 = (p1 < 7) ? p1 + 1 : 7;
        else if (bj == 2) p2 = (p2 < 7) ? p2 + 1 : 7;
        else p3 = (p3 < 7) ? p3 + 1 : 7;
        nbr[(size_t)rowid * KNB + it] = (int)(best & 0xffffffffu);
    }
}

// ------- prep mega-kernel: weight transposes (0..159) | f64 compositions (160..741) -------
__global__ __launch_bounds__(256) void prep_weights(
        const float* __restrict__ fc1_w, const float* __restrict__ fc2_w,
        const float* __restrict__ fce_w, const float* __restrict__ upd_w,
        const float* __restrict__ kp_w, const float* __restrict__ kp_b,
        const float* __restrict__ enc_w, const float* __restrict__ enc_b,
        const float* __restrict__ mu_w, const float* __restrict__ mu_b,
        const float* __restrict__ dec_w, const float* __restrict__ dec_b,
        const float* __restrict__ inout_w, const float* __restrict__ inout_b,
        const float* __restrict__ upd_b,
        __bf16* __restrict__ W1catT, __bf16* __restrict__ W2catT,
        __bf16* __restrict__ fcet, __bf16* __restrict__ updC,
        float* __restrict__ KW1, float* __restrict__ kb1,
        float* __restrict__ KW2, float* __restrict__ kb2,
        float* __restrict__ bcomp) {
    __shared__ float tile[64][65];
    int bid = blockIdx.x;
    int t = threadIdx.x;
    if (bid < 64) {
        const float* W = (bid < 32) ? fc1_w : fc2_w;
        __bf16* WT = (bid < 32) ? W1catT : W2catT;
        int local = bid & 31;
        int n0 = (local >> 2) * 64, k0 = (local & 3) * 64;
        #pragma unroll
        for (int s = 0; s < 16; ++s) {
            int idx = s * 256 + t;
            int kk = idx >> 6, nn = idx & 63;
            float v;
            if (n0 < 256)
                v = W[(size_t)(k0 + kk) * 256 + n0 + nn] -
                    W[(size_t)(k0 + kk + 256) * 256 + n0 + nn];
            else
                v = W[(size_t)(k0 + kk + 256) * 256 + (n0 - 256) + nn];
            tile[kk][nn] = v;
        }
        __syncthreads();
        #pragma unroll
        for (int s = 0; s < 16; ++s) {
            int idx = s * 256 + t;
            int nn = idx >> 6, kk = idx & 63;
            WT[(size_t)(n0 + nn) * 256 + k0 + kk] = (__bf16)tile[kk][nn];
        }
    } else if (bid < 96) {
        int local = bid - 64;
        int n0 = (local >> 2) * 64, k0 = (local & 3) * 64;
        #pragma unroll
        for (int s = 0; s < 16; ++s) {
            int idx = s * 256 + t;
            int kk = idx >> 6, nn = idx & 63;
            tile[kk][nn] = fce_w[(size_t)(k0 + kk) * 512 + n0 + nn];
        }
        __syncthreads();
        #pragma unroll
        for (int s = 0; s < 16; ++s) {
            int idx = s * 256 + t;
            int nn = idx >> 6, kk = idx & 63;
            fcet[(size_t)(n0 + nn) * 256 + k0 + kk] = (__bf16)tile[kk][nn];
        }
    } else if (bid < 160) {
        int local = bid - 96;                       // 0..63
        int k0 = (local >> 3) * 64, n0 = (local & 7) * 64;
        #pragma unroll
        for (int s = 0; s < 16; ++s) {
            int idx = s * 256 + t;
            int kk = idx >> 6, nn = idx & 63;
            tile[kk][nn] = upd_w[(size_t)(512 + k0 + kk) * 512 + n0 + nn];
        }
        __syncthreads();
        #pragma unroll
        for (int s = 0; s < 16; ++s) {
            int idx = s * 256 + t;
            int nn = idx >> 6, kk = idx & 63;
            updC[(size_t)(n0 + nn) * 768 + 256 + k0 + kk] = (__bf16)tile[kk][nn];
        }
    } else if (bid < 224) {
        int i = (bid - 160) * 4 + (t >> 6);
        int j = t & 63;
        double acc = 0.0;
        for (int k = 0; k < 500; ++k)
            acc += (double)kp_w[(size_t)i * 500 + k] * (double)enc_w[(size_t)k * 64 + j];
        KW1[i * 64 + j] = (float)acc;
    } else if (bid == 224) {
        int j = t;
        if (j < 64) {
            double acc = (double)enc_b[j];
            for (int k = 0; k < 500; ++k)
                acc += (double)kp_b[k] * (double)enc_w[(size_t)k * 64 + j];
            kb1[j] = (float)acc;
        }
    } else if (bid < 228) {
        int e = (bid - 225) * 256 + t;
        if (e < 576) {
            int i = e / 9, j = e - (e / 9) * 9;
            double acc = 0.0;
            for (int k = 0; k < 32; ++k)
                acc += (double)mu_w[(size_t)i * 32 + k] * (double)dec_w[(size_t)k * 9 + j];
            KW2[e] = (float)acc;
        } else if (e < 585) {
            int j = e - 576;
            double acc = (double)dec_b[j];
            for (int k = 0; k < 32; ++k)
                acc += (double)mu_b[k] * (double)dec_w[(size_t)k * 9 + j];
            kb2[j] = (float)acc;
        }
    } else if (bid < 740) {
        int e = (bid - 228) * 256 + t;              // 0..131071
        int k = e >> 9, n = e & 511;
        double acc = 0.0;
        for (int j = 0; j < 512; ++j)
            acc += (double)inout_w[(size_t)k * 512 + j] * (double)upd_w[(size_t)j * 512 + n];
        updC[(size_t)n * 768 + k] = (__bf16)(float)acc;
    } else {
        int n = (bid - 740) * 256 + t;              // 0..511
        double acc = (double)upd_b[n];
        for (int j = 0; j < 512; ++j)
            acc += (double)inout_b[j] * (double)upd_w[(size_t)j * 512 + n];
        bcomp[n] = (float)acc;
    }
}

// ------- combine: H[r] = (relu?)( deg*(Pa[self]+bias) + sum_nbr Pb ), XCD-swizzled -------
template<int STAGE, int RELU>
__global__ __launch_bounds__(256) void combine_kernel(const __bf16* __restrict__ P,
        const int* __restrict__ nbr, const int* __restrict__ kint_,
        const float* __restrict__ degf, const float* __restrict__ bias,
        __bf16* __restrict__ H) {
    int g = threadIdx.x >> 6, lane = threadIdx.x & 63;
    int nid = xcd_swz(blockIdx.x, 2 * ROWS / 4);
    int r = nid * 4 + g;                        // 0..2*ROWS
    int branch = (r >= ROWS);
    int rr = r - branch * ROWS;
    int b = rr / NPT, i = rr - b * NPT;
    size_t srow, mbase;
    if constexpr (STAGE == 1) {
        int fb = branch ? src_batch(b) : b;
        srow = (size_t)fb * NPT + i;
        mbase = (size_t)fb * NPT;
    } else {
        srow = (size_t)r;
        mbase = (size_t)branch * ROWS + (size_t)b * NPT;
    }
    const int* nb = nbr + (size_t)branch * ((size_t)ROWS * KNB) + (size_t)rr * KNB;
    bf16x4 sv = *(const bf16x4*)(P + srow * 512 + lane * 4);
    float4 bv = *(const float4*)(bias + lane * 4);
    float s0 = 0.f, s1 = 0.f, s2 = 0.f, s3 = 0.f;
    int kk = kint_[rr];
    for (int tt = 0; tt < kk; ++tt) {
        int m = nb[tt];
        bf16x4 v = *(const bf16x4*)(P + (mbase + m) * 512 + 256 + lane * 4);
        s0 += (float)v[0]; s1 += (float)v[1]; s2 += (float)v[2]; s3 += (float)v[3];
    }
    float dg = degf[rr];
    float o0 = fmaf(dg, (float)sv[0] + bv.x, s0);
    float o1 = fmaf(dg, (float)sv[1] + bv.y, s1);
    float o2 = fmaf(dg, (float)sv[2] + bv.z, s2);
    float o3 = fmaf(dg, (float)sv[3] + bv.w, s3);
    if constexpr (RELU) {
        o0 = fmaxf(o0, 0.f); o1 = fmaxf(o1, 0.f);
        o2 = fmaxf(o2, 0.f); o3 = fmaxf(o3, 0.f);
    }
    bf16x4 ov;
    ov[0] = (__bf16)o0; ov[1] = (__bf16)o1; ov[2] = (__bf16)o2; ov[3] = (__bf16)o3;
    *(bf16x4*)(H + (size_t)r * 256 + lane * 4) = ov;
}

// ---------------- bf16 MFMA GEMM (XCD-swizzled) ----------------
// FLAGS: 1=RELU, 4=bf16 out, 8=transposed out[b][c][i], 16=scores epilogue (implies bf16 out).
// CONCAT: 0 plain; 2 = A row = [A0(256) | wgt-mix of A1/A1+ROWS*512 (512)], K=768.
template<int FLAGS, int CONCAT>
__global__ __launch_bounds__(256) void mfma_gemm(
    const __bf16* __restrict__ A0, const __bf16* __restrict__ A1,
    const __bf16* __restrict__ WT, const float* __restrict__ bias,
    float* __restrict__ Cf, __bf16* __restrict__ Cb, int K, int N,
    const float* __restrict__ aw, float* __restrict__ scp,
    const float* __restrict__ wgt) {
    constexpr int SMEMB = (FLAGS & 8) ? (128 * 129 * 4) : (2 * 128 * 64 * 2);
    __shared__ __attribute__((aligned(16))) char smem[SMEMB];
    __bf16* As = (__bf16*)smem;
    __bf16* Bs = As + 128 * 64;
    int lin = blockIdx.x + 4 * blockIdx.y;
    int nid = xcd_swz(lin, 4 * gridDim.y);
    int bx = nid & 3, by = nid >> 2;
    int t = threadIdx.x, w = t >> 6, l = t & 63;
    int r0 = by * 128, c0 = bx * 128;
    int lr = l & 15, lg = l >> 4;
    int wr = (w >> 1) * 64, wc = (w & 1) * 64;
    f32x4 acc[4][4] = {};
    for (int k0 = 0; k0 < K; k0 += 64) {
        #pragma unroll
        for (int i = 0; i < 4; ++i) {
            int row = (w * 4 + i) * 8 + (l >> 3);
            int c8 = l & 7;
            if constexpr (CONCAT == 2) {
                if (k0 < 256) {
                    gload_lds16(A0 + (size_t)(r0 + row) * 256 + k0 + c8 * 8,
                                As + (w * 4 + i) * 512);
                } else {
                    int kk2 = k0 - 256 + c8 * 8;
                    size_t gr = (size_t)(r0 + row);
                    bf16x8 xa = *(const bf16x8*)(A1 + gr * 512 + kk2);
                    bf16x8 ya = *(const bf16x8*)(A1 + ((size_t)ROWS + gr) * 512 + kk2);
                    float wv = wgt[gr];
                    bf16x8 mx;
                    #pragma unroll
                    for (int j = 0; j < 8; ++j)
                        mx[j] = (__bf16)(wv * (float)xa[j] + (1.f - wv) * (float)ya[j]);
                    *(bf16x8*)(As + (w * 4 + i) * 512 + l * 8) = mx;
                }
            } else {
                gload_lds16(A0 + (size_t)(r0 + row) * K + k0 + c8 * 8,
                            As + (w * 4 + i) * 512);
            }
            gload_lds16(WT + (size_t)(c0 + row) * K + k0 + c8 * 8,
                        Bs + (w * 4 + i) * 512);
        }
        asm volatile("s_waitcnt vmcnt(0)" ::: "memory");
        __syncthreads();
        #pragma unroll
        for (int ks = 0; ks < 2; ++ks) {
            bf16x8 af[4], bfr[4];
            #pragma unroll
            for (int mi = 0; mi < 4; ++mi)
                af[mi] = *(const bf16x8*)(As + (wr + mi * 16 + lr) * 64 + ks * 32 + lg * 8);
            #pragma unroll
            for (int ni = 0; ni < 4; ++ni)
                bfr[ni] = *(const bf16x8*)(Bs + (wc + ni * 16 + lr) * 64 + ks * 32 + lg * 8);
            #pragma unroll
            for (int mi = 0; mi < 4; ++mi)
                #pragma unroll
                for (int ni = 0; ni < 4; ++ni)
                    acc[mi][ni] = __builtin_amdgcn_mfma_f32_16x16x32_bf16(
                        af[mi], bfr[ni], acc[mi][ni], 0, 0, 0);
        }
        __syncthreads();
    }
    if constexpr ((FLAGS & 8) != 0) {
        float* tile = (float*)smem;
        #pragma unroll
        for (int mi = 0; mi < 4; ++mi)
            #pragma unroll
            for (int r = 0; r < 4; ++r) {
                int rrow = wr + mi * 16 + lg * 4 + r;
                #pragma unroll
                for (int ni = 0; ni < 4; ++ni) {
                    int ccol = wc + ni * 16 + lr;
                    float v = acc[mi][ni][r];
                    if (bias) v += bias[c0 + ccol];
                    if constexpr ((FLAGS & 1) != 0) v = fmaxf(v, 0.f);
                    tile[rrow * 129 + ccol] = v;
                }
            }
        __syncthreads();
        int cc = t >> 6, rr2 = t & 63;
        #pragma unroll
        for (int cs = 0; cs < 128; cs += 4) {
            #pragma unroll
            for (int h = 0; h < 2; ++h) {
                int row = r0 + rr2 + h * 64;
                int bb = row / NPT, ii = row - bb * NPT;
                Cf[((size_t)bb * 512 + (c0 + cc + cs)) * NPT + ii] =
                    tile[(rr2 + h * 64) * 129 + cc + cs];
            }
        }
    } else if constexpr ((FLAGS & 16) != 0) {
        int half = (r0 >= ROWS) ? 1 : 0;
        float ps[4][4] = {};
        #pragma unroll
        for (int mi = 0; mi < 4; ++mi)
            #pragma unroll
            for (int r = 0; r < 4; ++r) {
                int row = r0 + wr + mi * 16 + lg * 4 + r;
                #pragma unroll
                for (int ni = 0; ni < 4; ++ni) {
                    int col = c0 + wc + ni * 16 + lr;
                    float v = acc[mi][ni][r] + bias[col];
                    Cb[(size_t)row * N + col] = (__bf16)v;
                    ps[mi][r] = fmaf(v, aw[half * 512 + col], ps[mi][r]);
                }
            }
        #pragma unroll
        for (int m = 1; m <= 8; m <<= 1)
            #pragma unroll
            for (int mi = 0; mi < 4; ++mi)
                #pragma unroll
                for (int r = 0; r < 4; ++r)
                    ps[mi][r] += __shfl_xor(ps[mi][r], m, 64);
        if (lr == 0) {
            int slot = half * 8 + bx * 2 + (w & 1);
            #pragma unroll
            for (int mi = 0; mi < 4; ++mi)
                #pragma unroll
                for (int r = 0; r < 4; ++r) {
                    int sr = r0 - half * ROWS + wr + mi * 16 + lg * 4 + r;
                    scp[(size_t)slot * ROWS + sr] = ps[mi][r];
                }
        }
    } else {
        #pragma unroll
        for (int mi = 0; mi < 4; ++mi) {
            #pragma unroll
            for (int r = 0; r < 4; ++r) {
                int row = r0 + wr + mi * 16 + lg * 4 + r;
                #pragma unroll
                for (int ni = 0; ni < 4; ++ni) {
                    int col = c0 + wc + ni * 16 + lr;
                    float v = acc[mi][ni][r];
                    if (bias) v += bias[col];
                    if constexpr ((FLAGS & 1) != 0) v = fmaxf(v, 0.f);
                    if constexpr ((FLAGS & 4) != 0)
                        Cb[(size_t)row * N + col] = (__bf16)v;
                    else
                        Cf[(size_t)row * N + col] = v;
                }
            }
        }
    }
}

// ------- softmax stage 1 -------
__global__ __launch_bounds__(256) void softmax_part(const float* __restrict__ scp,
        const float* __restrict__ ab, float* __restrict__ scores,
        float* __restrict__ mpart, float* __restrict__ spart) {
    __shared__ float red[256];
    int t = threadIdx.x;
    int sr = blockIdx.x * 256 + t;              // 49*256 = ROWS exactly
    float s = ab[0];
    #pragma unroll
    for (int i = 0; i < 16; ++i) s += scp[(size_t)i * ROWS + sr];
    scores[sr] = s;
    red[t] = s; __syncthreads();
    for (int off = 128; off; off >>= 1) {
        if (t < off) red[t] = fmaxf(red[t], red[t + off]);
        __syncthreads();
    }
    float mb = red[0]; __syncthreads();
    red[t] = expf(s - mb); __syncthreads();
    for (int off = 128; off; off >>= 1) {
        if (t < off) red[t] += red[t + off];
        __syncthreads();
    }
    if (t == 0) { mpart[blockIdx.x] = mb; spart[blockIdx.x] = red[0]; }
}

// ------- softmax stage 2 -------
__global__ __launch_bounds__(256) void softmax_fin(const float* __restrict__ mpart,
        const float* __restrict__ spart, const float* __restrict__ scores,
        float* __restrict__ wgt) {
    __shared__ float MS[2];
    if (threadIdx.x == 0) {
        float M = mpart[0];
        for (int i = 1; i < 49; ++i) M = fmaxf(M, mpart[i]);
        float S = 0.f;
        for (int i = 0; i < 49; ++i) S += spart[i] * expf(mpart[i] - M);
        MS[0] = M; MS[1] = S;
    }
    __syncthreads();
    float M = MS[0], denom = MS[1];
    for (int i = threadIdx.x; i < ROWS; i += 256)
        wgt[i] = expf(scores[i] - M) / denom;
}

extern "C" void kernel_launch(void* const* d_in, const int* in_sizes, int n_in,
                              void* d_out, int out_size, void* d_ws, size_t ws_size,
                              hipStream_t stream) {
    (void)in_sizes; (void)n_in; (void)out_size; (void)ws_size;
    const float* x       = (const float*)d_in[0];
    const float* fc1_w   = (const float*)d_in[1];
    const float* fc1_b   = (const float*)d_in[2];
    const float* fc2_w   = (const float*)d_in[3];
    const float* fc2_b   = (const float*)d_in[4];
    const float* fce_w   = (const float*)d_in[5];
    const float* fce_b   = (const float*)d_in[6];
    const float* inout_w = (const float*)d_in[7];
    const float* inout_b = (const float*)d_in[8];
    const float* attn_w  = (const float*)d_in[9];
    const float* attn_b  = (const float*)d_in[10];
    const float* upd_w   = (const float*)d_in[11];
    const float* upd_b   = (const float*)d_in[12];
    const float* kp_w    = (const float*)d_in[13];
    const float* kp_b    = (const float*)d_in[14];
    const float* enc_w   = (const float*)d_in[15];
    const float* enc_b   = (const float*)d_in[16];
    const float* mu_w    = (const float*)d_in[17];
    const float* mu_b    = (const float*)d_in[18];
    const float* dec_w   = (const float*)d_in[19];
    const float* dec_b   = (const float*)d_in[20];
    float* out = (float*)d_out;

    char* base = (char*)d_ws;
    size_t o = 0;
    auto alloc = [&](size_t bytes) -> void* {
        void* p = base + o;
        o += (bytes + 255) & ~(size_t)255;
        return p;
    };
    float* qs     = (float*)alloc(ROWS * 4);
    float* degf   = (float*)alloc(ROWS * 4);
    float* scores = (float*)alloc(ROWS * 4);
    float* wgt    = (float*)alloc(ROWS * 4);
    int*   kint   = (int*)  alloc(ROWS * 4);
    float* KW1    = (float*)alloc(256 * 64 * 4);
    float* kb1    = (float*)alloc(64 * 4);
    float* KW2    = (float*)alloc(64 * 9 * 4);
    float* kb2    = (float*)alloc(9 * 4);
    float* bcomp  = (float*)alloc(512 * 4);
    float* scp    = (float*)alloc((size_t)16 * ROWS * 4);           //  0.80 MB
    float* mpart  = (float*)alloc(64 * 4);
    float* spart  = (float*)alloc(64 * 4);
    int*   nbr    = (int*)  alloc((size_t)128 * NPT * KNB * 4);     //  0.80 MB
    u64*   cand   = (u64*)  alloc((size_t)128 * NPT * 4 * 8 * 8);   //  6.42 MB
    char*  regD   = (char*) alloc((size_t)ROWS * 512 * 2);          // 12.85 MB
    __bf16* XB    = (__bf16*)alloc((size_t)ROWS * 256 * 2);         //  6.42 MB
    __bf16* H1    = (__bf16*)alloc((size_t)2 * ROWS * 256 * 2);     // 12.85 MB
    __bf16* H2    = (__bf16*)alloc((size_t)2 * ROWS * 256 * 2);     // 12.85 MB
    char*  regAGG = (char*) alloc((size_t)2 * ROWS * 512 * 4);      // 51.38 MB
    __bf16* W1catT= (__bf16*)alloc((size_t)512 * 256 * 2);
    __bf16* W2catT= (__bf16*)alloc((size_t)512 * 256 * 2);
    __bf16* fcet  = (__bf16*)alloc((size_t)512 * 256 * 2);
    __bf16* updC  = (__bf16*)alloc((size_t)512 * 768 * 2);
    // --- aliases (stream-order safe) ---
    __bf16* P1buf = (__bf16*)regD;                 // stage-1 P, dead after combine1
    _Float16* XSPH = (_Float16*)regAGG;            // dead after gram
    _Float16* XSPL = XSPH + (size_t)64 * 256 * 256;
    __bf16* P2buf = (__bf16*)regAGG;               // stage-2 P, dead after combine2
    __bf16* AGGb  = (__bf16*)regAGG;               // fce output (bf16), 25.7 MB
    __bf16* XAGGb = AGGb;

    // ---- prep (weights + composed k-predictor) ----
    prep_weights<<<742, 256, 0, stream>>>(fc1_w, fc2_w, fce_w, upd_w,
                                          kp_w, kp_b, enc_w, enc_b,
                                          mu_w, mu_b, dec_w, dec_b,
                                          inout_w, inout_b, upd_b,
                                          W1catT, W2catT, fcet, updC,
                                          KW1, kb1, KW2, kb2, bcomp);
    // ---- front (trans_split + qs + collapsed k-predictor) ----
    front_kernel<<<1872, 256, 0, stream>>>(x, XSPH, XSPL, XB, qs,
                                           KW1, kb1, KW2, kb2, kint, degf);

    // ---- KNN: gram with fused per-tile top-8 (DPP), then 4-way merge ----
    gram_mfma<<<dim3(2, 2, 128), 256, 0, stream>>>(XSPH, XSPL, qs, cand);
    topk_merge<<<98, 256, 0, stream>>>(cand, nbr);

    // ---- EdgeConv stage 1 ----
    mfma_gemm<4, 0><<<dim3(4, 98), 256, 0, stream>>>(
        XB, nullptr, W1catT, nullptr, nullptr, P1buf, 256, 512,
        nullptr, nullptr, nullptr);
    combine_kernel<1, 1><<<2 * ROWS / 4, 256, 0, stream>>>(
        P1buf, nbr, kint, degf, fc1_b, H1);

    // ---- EdgeConv stage 2 ----
    mfma_gemm<4, 0><<<dim3(4, 196), 256, 0, stream>>>(
        H1, nullptr, W2catT, nullptr, nullptr, P2buf, 256, 512,
        nullptr, nullptr, nullptr);
    combine_kernel<2, 0><<<2 * ROWS / 4, 256, 0, stream>>>(
        P2buf, nbr, kint, degf, fc2_b, H2);

    // ---- fce (bf16 out + fused attention-score partials) ----
    mfma_gemm<20, 0><<<dim3(4, 196), 256, 0, stream>>>(
        H2, nullptr, fcet, fce_b, nullptr, AGGb, 256, 512,
        attn_w, scp, nullptr);

    // ---- softmax (parallel, deterministic) ----
    softmax_part<<<49, 256, 0, stream>>>(scp, attn_b, scores, mpart, spart);
    softmax_fin<<<1, 256, 0, stream>>>(mpart, spart, scores, wgt);

    // ---- final upd GEMM: inline wgt-mix A-staging, composed inout, transposed out ----
    mfma_gemm<9, 2><<<dim3(4, 98), 256, 0, stream>>>(
        XB, XAGGb, updC, bcomp, out, nullptr, 768, 512,
        nullptr, nullptr, wgt);
}